// Round 10
// baseline (2494.482 us; speedup 1.0000x reference)
//
#include <hip/hip_runtime.h>
#include <stdint.h>

#define NROWS 32768   // 32*1024
#define DIM   512
#define NEMB  8192

#define BM 128
#define BN 128
#define BK 32
#define MARGIN 1.0e-4f   // validated r6/r7/r9
#define OVF_CAP (1 << 20)

// ws layout (fast path):
//   [0,        262144) : ull best[NROWS]   final key = (f2ord(exact_d)<<32)|idx
//   [262144,   393216) : float x2f[NROWS]
//   [393216,   393224) : double loss_accum
//   [393224,   393228) : u32 ovf_cnt
//   [524288,  8912896) : Eb  bf16 swizzled [8192][512]
//   [8912896,42467328) : Xb  bf16 swizzled [32768][512]
//   [42467328,59244544): ull slots[32768][64]  (f2ord(s~)<<32)|col per (row,panel)
//   [59244544,63438848): u32 ovf[1M]  (row<<13)|col
#define WS_NEED_R9 42467328ull
#define WS_NEED    63438848ull
//
// Reference model (validated rounds 4-9, PASSED 6x): ref d = fl32(x2-2*M),
// M = k-sequential f32 FMA chain; e2 vanishes under fl32(x2+e2); argmin
// first-occurrence = lowest index on bit-equal d.
//
// r10: refine protocol split. r9 post-mortem: VALUBusy 18.5% == the exact
// 512-FMA chains (H(64) stale-best refines/row x 512 fmaf ≈ 1e8 VALU ops);
// 4-cyc dep chains made them the wave critical path -> K-loop schedule
// changes were no-ops (r7≈r9). Pass A now emits only block-row-min slots
// (+rare overflow); pass B reduces 64 slots/row and chains only multi-
// candidate rows with one candidate per lane (parallel chains).

typedef short bf16x8 __attribute__((ext_vector_type(8)));   // 8 bf16 (4 VGPRs)
typedef float f32x4  __attribute__((ext_vector_type(4)));

#define LDSP(p) (__attribute__((address_space(3))) unsigned int*)(p)
#define GLP(p)  (const __attribute__((address_space(1))) unsigned int*)(p)

__device__ __forceinline__ unsigned int f2ord(float f) {
    unsigned int b = __float_as_uint(f);
    return b ^ ((b & 0x80000000u) ? 0xFFFFFFFFu : 0x80000000u);
}
__device__ __forceinline__ float ord2f(unsigned int o) {
    unsigned int b = (o & 0x80000000u) ? (o ^ 0x80000000u) : ~o;
    return __uint_as_float(b);
}
__device__ __forceinline__ unsigned short f2b(float f) {   // f32 -> bf16 RNE
    unsigned int u = __float_as_uint(f);
    u += 0x7FFFu + ((u >> 16) & 1u);
    return (unsigned short)(u >> 16);
}

// exact d for (row,col): the reference-matching sequential-k f32 FMA chain.
__device__ __forceinline__ float exact_d(const float* __restrict__ X,
                                         const float* __restrict__ E,
                                         const float* __restrict__ x2f,
                                         int row, int col) {
    const float* xp = X + (size_t)row * DIM;
    const float* ep = E + (size_t)col * DIM;
    float dot = 0.f;
    #pragma unroll 4
    for (int k = 0; k < DIM; k += 4) {
        float4 a  = *(const float4*)(xp + k);
        float4 bb = *(const float4*)(ep + k);
        dot = fmaf(a.x, bb.x, dot); dot = fmaf(a.y, bb.y, dot);
        dot = fmaf(a.z, bb.z, dot); dot = fmaf(a.w, bb.w, dot);
    }
    return x2f[row] - 2.0f * dot;
}

// ||x_row||^2 in f64, rounded to f32 — unchanged (passed 6x)
__global__ __launch_bounds__(256)
void x2_kernel(const float* __restrict__ X, float* __restrict__ x2f) {
    int w = (int)((blockIdx.x * blockDim.x + threadIdx.x) >> 6);
    int lane = threadIdx.x & 63;
    if (w >= NROWS) return;
    const float4* row = (const float4*)(X + (size_t)w * DIM);
    double s = 0.0;
    #pragma unroll
    for (int i = 0; i < 2; ++i) {
        float4 v = row[lane + i * 64];
        s += (double)v.x * v.x + (double)v.y * v.y
           + (double)v.z * v.z + (double)v.w * v.w;
    }
    #pragma unroll
    for (int off = 32; off; off >>= 1) s += __shfl_down(s, off, 64);
    if (lane == 0) x2f[w] = (float)s;
}

// f32 -> bf16 RNE convert with chunk swizzle v2 — unchanged (passed r7-r9)
__global__ __launch_bounds__(256)
void conv_kernel(const float* __restrict__ src, unsigned short* __restrict__ dst,
                 int total) {
    int tid = blockIdx.x * 256 + threadIdx.x;
    if (tid >= total) return;
    int r   = tid >> 6;
    int cg  = tid & 63;
    int seg = cg >> 2, c = cg & 3;
    const float4* s = (const float4*)(src + (size_t)r * DIM + cg * 8);
    float4 v0 = s[0], v1 = s[1];
    unsigned int w0 = (unsigned)f2b(v0.x) | ((unsigned)f2b(v0.y) << 16);
    unsigned int w1 = (unsigned)f2b(v0.z) | ((unsigned)f2b(v0.w) << 16);
    unsigned int w2 = (unsigned)f2b(v1.x) | ((unsigned)f2b(v1.y) << 16);
    unsigned int w3 = (unsigned)f2b(v1.z) | ((unsigned)f2b(v1.w) << 16);
    int dchunk = seg * 4 + (c ^ ((r >> 1) & 3));
    *(uint4*)(dst + (size_t)r * DIM + dchunk * 8) = make_uint4(w0, w1, w2, w3);
}

// Pass A: 128^2 bf16 GEMM (r9 K-loop verbatim) -> per-(row,panel) min slot.
__global__ __launch_bounds__(256)
void dist_passA_kernel(const unsigned short* __restrict__ Xb,
                       const unsigned short* __restrict__ Eb,
                       unsigned long long* __restrict__ slots,
                       unsigned int* __restrict__ ovf,
                       unsigned int* __restrict__ ovf_cnt) {
    __shared__ unsigned short As[3][BM][BK];   // 3 x 8 KB, LINEAR (DMA dest)
    __shared__ unsigned short Bs[3][BN][BK];   // 3 x 8 KB
    __shared__ unsigned long long smin64[BM];  // (f2ord(s~)<<32)|col

    const int t    = threadIdx.x;
    const int lane = t & 63;
    const int wid  = t >> 6;
    const int wm   = (wid >> 1) * 64;
    const int wn   = (wid & 1) * 64;
    const int rowBase = blockIdx.x * BM;
    const int colBase = blockIdx.y * BN;

    if (t < BM) smin64[t] = 0xFFFFFFFFFFFFFFFFull;

    const char* aSrc = (const char*)Xb
        + (size_t)(rowBase + wid * 16 + (lane >> 2)) * 1024 + (size_t)(lane & 3) * 16;
    const char* bSrc = (const char*)Eb
        + (size_t)(colBase + wid * 16 + (lane >> 2)) * 1024 + (size_t)(lane & 3) * 16;

    const int fswz = (((lane >> 4) ^ ((lane >> 1) & 3)) << 4);
    const int aOff = (wm + (lane & 15)) * 64 + fswz;
    const int bOff = (wn + (lane & 15)) * 64 + fswz;

    f32x4 acc[4][4] = {};

#define ISSUE_TILE(KT, BUF) do {                                               \
        const char* an_ = aSrc + (KT) * 64;                                    \
        const char* bn_ = bSrc + (KT) * 64;                                    \
        __builtin_amdgcn_global_load_lds(GLP(an_),         LDSP(&As[BUF][wid * 16][0]),      16, 0, 0); \
        __builtin_amdgcn_global_load_lds(GLP(an_ + 65536), LDSP(&As[BUF][64 + wid * 16][0]), 16, 0, 0); \
        __builtin_amdgcn_global_load_lds(GLP(bn_),         LDSP(&Bs[BUF][wid * 16][0]),      16, 0, 0); \
        __builtin_amdgcn_global_load_lds(GLP(bn_ + 65536), LDSP(&Bs[BUF][64 + wid * 16][0]), 16, 0, 0); \
    } while (0)

#define COMPUTE_TILE(BUF) do {                                                 \
        const char* aR_ = (const char*)&As[BUF][0][0] + aOff;                  \
        const char* bR_ = (const char*)&Bs[BUF][0][0] + bOff;                  \
        bf16x8 af_[4], bg_[4];                                                 \
        _Pragma("unroll")                                                      \
        for (int mi = 0; mi < 4; ++mi)                                         \
            af_[mi] = *(const bf16x8*)(aR_ + mi * 16 * 64);                    \
        _Pragma("unroll")                                                      \
        for (int nj = 0; nj < 4; ++nj)                                         \
            bg_[nj] = *(const bf16x8*)(bR_ + nj * 16 * 64);                    \
        _Pragma("unroll")                                                      \
        for (int mi = 0; mi < 4; ++mi)                                         \
            _Pragma("unroll")                                                  \
            for (int nj = 0; nj < 4; ++nj)                                     \
                acc[mi][nj] = __builtin_amdgcn_mfma_f32_16x16x32_bf16(         \
                    af_[mi], bg_[nj], acc[mi][nj], 0, 0, 0);                   \
    } while (0)

#define K_STEP(KT, WAITSTR) do {                                               \
        if ((KT) + 2 < 16) ISSUE_TILE((KT) + 2, ((KT) + 2) % 3);               \
        asm volatile("s_waitcnt vmcnt(" WAITSTR ")" ::: "memory");             \
        __builtin_amdgcn_s_barrier();                                          \
        COMPUTE_TILE((KT) % 3);                                                \
        asm volatile("s_waitcnt lgkmcnt(0)" ::: "memory");                     \
        __builtin_amdgcn_s_barrier();                                          \
    } while (0)

    ISSUE_TILE(0, 0);
    ISSUE_TILE(1, 1);

    K_STEP(0,  "8");  K_STEP(1,  "8");  K_STEP(2,  "8");  K_STEP(3,  "8");
    K_STEP(4,  "8");  K_STEP(5,  "8");  K_STEP(6,  "8");  K_STEP(7,  "8");
    K_STEP(8,  "8");  K_STEP(9,  "8");  K_STEP(10, "8");  K_STEP(11, "8");
    K_STEP(12, "8");  K_STEP(13, "8");  K_STEP(14, "4");  K_STEP(15, "0");

#undef K_STEP
#undef COMPUTE_TILE
#undef ISSUE_TILE

    // ---- block-row min key into LDS (shfl over the 16-lane col group) ----
    #pragma unroll
    for (int mi = 0; mi < 4; ++mi)
        #pragma unroll
        for (int r = 0; r < 4; ++r) {
            unsigned long long k = 0xFFFFFFFFFFFFFFFFull;
            #pragma unroll
            for (int nj = 0; nj < 4; ++nj) {
                float s = -2.f * acc[mi][nj][r];
                unsigned long long kk = ((unsigned long long)f2ord(s) << 32)
                                      | (unsigned)(colBase + wn + nj * 16 + (lane & 15));
                if (kk < k) k = kk;
            }
            #pragma unroll
            for (int sh = 1; sh < 16; sh <<= 1) {
                unsigned long long o = __shfl_xor(k, sh, 64);
                if (o < k) k = o;
            }
            if ((lane & 15) == 0)
                atomicMin(&smin64[wm + mi * 16 + (lane >> 4) * 4 + r], k);
        }
    __syncthreads();

    // ---- slot write + overflow append (non-winner cells within MARGIN) ----
    if (t < BM)
        slots[(size_t)(rowBase + t) * 64 + blockIdx.y] = smin64[t];

    #pragma unroll
    for (int mi = 0; mi < 4; ++mi)
        #pragma unroll
        for (int r = 0; r < 4; ++r) {
            int rt = wm + mi * 16 + (lane >> 4) * 4 + r;
            unsigned long long w = smin64[rt];
            float thr = ord2f((unsigned)(w >> 32)) + MARGIN;
            #pragma unroll
            for (int nj = 0; nj < 4; ++nj) {
                float s = -2.f * acc[mi][nj][r];
                unsigned col = (unsigned)(colBase + wn + nj * 16 + (lane & 15));
                unsigned long long kk = ((unsigned long long)f2ord(s) << 32) | col;
                if (s <= thr && kk != w) {
                    unsigned idx = atomicAdd(ovf_cnt, 1u);
                    if (idx < OVF_CAP)
                        ovf[idx] = ((unsigned)(rowBase + rt) << 13) | col;
                }
            }
        }
}

// Overflow refine: parallel exact chains, one per lane, grid-stride.
__global__ __launch_bounds__(256)
void ovf_kernel(const float* __restrict__ X, const float* __restrict__ E,
                const float* __restrict__ x2f,
                const unsigned int* __restrict__ ovf,
                const unsigned int* __restrict__ ovf_cnt,
                unsigned long long* __restrict__ best) {
    unsigned n = *ovf_cnt;
    if (n > OVF_CAP) n = OVF_CAP;
    for (unsigned i = blockIdx.x * 256 + threadIdx.x; i < n; i += gridDim.x * 256) {
        unsigned p = ovf[i];
        int row = (int)(p >> 13), col = (int)(p & 8191u);
        float d = exact_d(X, E, x2f, row, col);
        unsigned long long key = ((unsigned long long)f2ord(d) << 32) | (unsigned)col;
        atomicMin(&best[row], key);
    }
}

// Pass B: per-row slot reduce; single-candidate fast path; else parallel chains.
__global__ __launch_bounds__(256)
void reduce_kernel(const float* __restrict__ X, const float* __restrict__ E,
                   const float* __restrict__ x2f,
                   const unsigned long long* __restrict__ slots,
                   unsigned long long* __restrict__ best) {
    const int t    = threadIdx.x;
    const int lane = t & 63;
    const int row  = blockIdx.x * 4 + (t >> 6);

    unsigned long long sl = slots[(size_t)row * 64 + lane];
    unsigned long long m = sl;
    #pragma unroll
    for (int sh = 1; sh < 64; sh <<= 1) {
        unsigned long long o = __shfl_xor(m, sh, 64);
        if (o < m) m = o;
    }
    float thr = ord2f((unsigned)(m >> 32)) + MARGIN;
    float smy = ord2f((unsigned)(sl >> 32));      // sentinel -> NaN -> not cand
    bool cand = (smy <= thr);
    unsigned long long bal = __ballot(cand);
    unsigned long long bb = best[row];

    if (bb == 0xFFFFFFFFFFFFFFFFull && __popcll(bal) == 1) {
        if (cand) best[row] = sl;                 // unique winner, no chain
    } else if (cand) {
        int col = (int)(sl & 0xFFFFFFFFull);
        float d = exact_d(X, E, x2f, row, col);
        unsigned long long key = ((unsigned long long)f2ord(d) << 32) | (unsigned)col;
        atomicMin(&best[row], key);
    }
}

// ---------- r9 fast kernel kept as mid fallback (ws in [42.5MB, 63.4MB)) ----
__global__ __launch_bounds__(256)
void dist_mfma3_kernel(const float* __restrict__ X, const float* __restrict__ E,
                       const unsigned short* __restrict__ Xb,
                       const unsigned short* __restrict__ Eb,
                       const float* __restrict__ x2f,
                       unsigned long long* __restrict__ best) {
    __shared__ unsigned short As[3][BM][BK];
    __shared__ unsigned short Bs[3][BN][BK];
    __shared__ unsigned int   smin[BM];

    const int t    = threadIdx.x;
    const int lane = t & 63;
    const int wid  = t >> 6;
    const int wm   = (wid >> 1) * 64;
    const int wn   = (wid & 1) * 64;
    const int rowBase = blockIdx.x * BM;
    const int colBase = blockIdx.y * BN;

    if (t < BM) smin[t] = 0xFFFFFFFFu;

    const char* aSrc = (const char*)Xb
        + (size_t)(rowBase + wid * 16 + (lane >> 2)) * 1024 + (size_t)(lane & 3) * 16;
    const char* bSrc = (const char*)Eb
        + (size_t)(colBase + wid * 16 + (lane >> 2)) * 1024 + (size_t)(lane & 3) * 16;

    const int fswz = (((lane >> 4) ^ ((lane >> 1) & 3)) << 4);
    const int aOff = (wm + (lane & 15)) * 64 + fswz;
    const int bOff = (wn + (lane & 15)) * 64 + fswz;

    f32x4 acc[4][4] = {};

#define ISSUE_TILE(KT, BUF) do {                                               \
        const char* an_ = aSrc + (KT) * 64;                                    \
        const char* bn_ = bSrc + (KT) * 64;                                    \
        __builtin_amdgcn_global_load_lds(GLP(an_),         LDSP(&As[BUF][wid * 16][0]),      16, 0, 0); \
        __builtin_amdgcn_global_load_lds(GLP(an_ + 65536), LDSP(&As[BUF][64 + wid * 16][0]), 16, 0, 0); \
        __builtin_amdgcn_global_load_lds(GLP(bn_),         LDSP(&Bs[BUF][wid * 16][0]),      16, 0, 0); \
        __builtin_amdgcn_global_load_lds(GLP(bn_ + 65536), LDSP(&Bs[BUF][64 + wid * 16][0]), 16, 0, 0); \
    } while (0)

#define COMPUTE_TILE(BUF) do {                                                 \
        const char* aR_ = (const char*)&As[BUF][0][0] + aOff;                  \
        const char* bR_ = (const char*)&Bs[BUF][0][0] + bOff;                  \
        bf16x8 af_[4], bg_[4];                                                 \
        _Pragma("unroll")                                                      \
        for (int mi = 0; mi < 4; ++mi)                                         \
            af_[mi] = *(const bf16x8*)(aR_ + mi * 16 * 64);                    \
        _Pragma("unroll")                                                      \
        for (int nj = 0; nj < 4; ++nj)                                         \
            bg_[nj] = *(const bf16x8*)(bR_ + nj * 16 * 64);                    \
        _Pragma("unroll")                                                      \
        for (int mi = 0; mi < 4; ++mi)                                         \
            _Pragma("unroll")                                                  \
            for (int nj = 0; nj < 4; ++nj)                                     \
                acc[mi][nj] = __builtin_amdgcn_mfma_f32_16x16x32_bf16(         \
                    af_[mi], bg_[nj], acc[mi][nj], 0, 0, 0);                   \
    } while (0)

#define K_STEP(KT, WAITSTR) do {                                               \
        if ((KT) + 2 < 16) ISSUE_TILE((KT) + 2, ((KT) + 2) % 3);               \
        asm volatile("s_waitcnt vmcnt(" WAITSTR ")" ::: "memory");             \
        __builtin_amdgcn_s_barrier();                                          \
        COMPUTE_TILE((KT) % 3);                                                \
        asm volatile("s_waitcnt lgkmcnt(0)" ::: "memory");                     \
        __builtin_amdgcn_s_barrier();                                          \
    } while (0)

    ISSUE_TILE(0, 0);
    ISSUE_TILE(1, 1);

    K_STEP(0,  "8");  K_STEP(1,  "8");  K_STEP(2,  "8");  K_STEP(3,  "8");
    K_STEP(4,  "8");  K_STEP(5,  "8");  K_STEP(6,  "8");  K_STEP(7,  "8");
    K_STEP(8,  "8");  K_STEP(9,  "8");  K_STEP(10, "8");  K_STEP(11, "8");
    K_STEP(12, "8");  K_STEP(13, "8");  K_STEP(14, "4");  K_STEP(15, "0");

#undef K_STEP
#undef COMPUTE_TILE
#undef ISSUE_TILE

    #pragma unroll
    for (int mi = 0; mi < 4; ++mi)
        #pragma unroll
        for (int r = 0; r < 4; ++r) {
            float m4 = fminf(fminf(-2.f * acc[mi][0][r], -2.f * acc[mi][1][r]),
                             fminf(-2.f * acc[mi][2][r], -2.f * acc[mi][3][r]));
            unsigned u = f2ord(m4);
            #pragma unroll
            for (int sh = 1; sh < 16; sh <<= 1)
                u = min(u, (unsigned)__shfl_xor((int)u, sh, 64));
            if ((lane & 15) == 0)
                atomicMin(&smin[wm + mi * 16 + (lane >> 4) * 4 + r], u);
        }
    __syncthreads();

    unsigned long long mask = 0;
    #pragma unroll
    for (int mi = 0; mi < 4; ++mi)
        #pragma unroll
        for (int r = 0; r < 4; ++r) {
            int rt  = wm + mi * 16 + (lane >> 4) * 4 + r;
            int row = rowBase + rt;
            float x2v = x2f[row];
            float dg  = ord2f((unsigned)(best[row] >> 32));
            float th  = fminf(ord2f(smin[rt]), dg - x2v) + MARGIN;
            #pragma unroll
            for (int nj = 0; nj < 4; ++nj) {
                float s = -2.f * acc[mi][nj][r];
                if (s <= th) mask |= 1ull << (mi * 16 + nj * 4 + r);
            }
        }

    while (mask) {
        int b = __builtin_ctzll(mask);
        mask &= mask - 1;
        int mi = b >> 4, nj = (b >> 2) & 3, r = b & 3;
        int row = rowBase + wm + mi * 16 + (lane >> 4) * 4 + r;
        int col = colBase + wn + nj * 16 + (lane & 15);
        float d = exact_d(X, E, x2f, row, col);
        unsigned long long key = ((unsigned long long)f2ord(d) << 32) | (unsigned)col;
        atomicMin(&best[row], key);
    }
}

// ---------- round-5 kernel kept as last-resort fallback ----------
__global__ __launch_bounds__(256)
void dist_mfma_kernel(const float* __restrict__ X, const float* __restrict__ E,
                      const float* __restrict__ x2f,
                      unsigned long long* __restrict__ best) {
    __shared__ unsigned short Asf[BM][40];
    __shared__ unsigned short Bsf[BN][40];
    __shared__ unsigned int   smin[BM];

    const int t    = threadIdx.x;
    const int lane = t & 63;
    const int wid  = t >> 6;
    const int wm   = (wid >> 1) * 64;
    const int wn   = (wid & 1) * 64;
    const int rowBase = blockIdx.x * BM;
    const int colBase = blockIdx.y * BN;

    if (t < BM) smin[t] = 0xFFFFFFFFu;

    const int srow = t >> 3;
    const int sf4  = t & 7;

    f32x4 acc[4][4] = {};
    float4 ra[4], rb[4];

    #pragma unroll
    for (int p = 0; p < 4; ++p) {
        ra[p] = *(const float4*)(X + (size_t)(rowBase + p * 32 + srow) * DIM + sf4 * 4);
        rb[p] = *(const float4*)(E + (size_t)(colBase + p * 32 + srow) * DIM + sf4 * 4);
    }

    for (int kt = 0; kt < DIM / BK; ++kt) {
        __syncthreads();
        #pragma unroll
        for (int p = 0; p < 4; ++p) {
            int r = p * 32 + srow;
            unsigned int alo = (unsigned)f2b(ra[p].x) | ((unsigned)f2b(ra[p].y) << 16);
            unsigned int ahi = (unsigned)f2b(ra[p].z) | ((unsigned)f2b(ra[p].w) << 16);
            *(uint2*)&Asf[r][sf4 * 4] = make_uint2(alo, ahi);
            unsigned int blo = (unsigned)f2b(rb[p].x) | ((unsigned)f2b(rb[p].y) << 16);
            unsigned int bhi = (unsigned)f2b(rb[p].z) | ((unsigned)f2b(rb[p].w) << 16);
            *(uint2*)&Bsf[r][sf4 * 4] = make_uint2(blo, bhi);
        }
        __syncthreads();

        if (kt + 1 < DIM / BK) {
            int k0 = (kt + 1) * BK;
            #pragma unroll
            for (int p = 0; p < 4; ++p) {
                ra[p] = *(const float4*)(X + (size_t)(rowBase + p * 32 + srow) * DIM + k0 + sf4 * 4);
                rb[p] = *(const float4*)(E + (size_t)(colBase + p * 32 + srow) * DIM + k0 + sf4 * 4);
            }
        }

        bf16x8 af[4], bg[4];
        #pragma unroll
        for (int mi = 0; mi < 4; ++mi)
            af[mi] = *(const bf16x8*)&Asf[wm + mi * 16 + (lane & 15)][(lane >> 4) * 8];
        #pragma unroll
        for (int nj = 0; nj < 4; ++nj)
            bg[nj] = *(const bf16x8*)&Bsf[wn + nj * 16 + (lane & 15)][(lane >> 4) * 8];
        #pragma unroll
        for (int mi = 0; mi < 4; ++mi)
            #pragma unroll
            for (int nj = 0; nj < 4; ++nj)
                acc[mi][nj] = __builtin_amdgcn_mfma_f32_16x16x32_bf16(
                    af[mi], bg[nj], acc[mi][nj], 0, 0, 0);
    }

    #pragma unroll
    for (int mi = 0; mi < 4; ++mi)
        #pragma unroll
        for (int r = 0; r < 4; ++r) {
            float m4 = fminf(fminf(-2.f * acc[mi][0][r], -2.f * acc[mi][1][r]),
                             fminf(-2.f * acc[mi][2][r], -2.f * acc[mi][3][r]));
            unsigned u = f2ord(m4);
            #pragma unroll
            for (int sh = 1; sh < 16; sh <<= 1)
                u = min(u, (unsigned)__shfl_xor((int)u, sh, 64));
            if ((lane & 15) == 0)
                atomicMin(&smin[wm + mi * 16 + (lane >> 4) * 4 + r], u);
        }
    __syncthreads();

    unsigned long long mask = 0;
    #pragma unroll
    for (int mi = 0; mi < 4; ++mi)
        #pragma unroll
        for (int r = 0; r < 4; ++r) {
            int rt  = wm + mi * 16 + (lane >> 4) * 4 + r;
            int row = rowBase + rt;
            float x2v = x2f[row];
            float dg  = ord2f((unsigned)(best[row] >> 32));
            float th  = fminf(ord2f(smin[rt]), dg - x2v) + 1.5e-3f;
            #pragma unroll
            for (int nj = 0; nj < 4; ++nj) {
                float s = -2.f * acc[mi][nj][r];
                if (s <= th) mask |= 1ull << (mi * 16 + nj * 4 + r);
            }
        }

    while (mask) {
        int b = __builtin_ctzll(mask);
        mask &= mask - 1;
        int mi = b >> 4, nj = (b >> 2) & 3, r = b & 3;
        int row = rowBase + wm + mi * 16 + (lane >> 4) * 4 + r;
        int col = colBase + wn + nj * 16 + (lane & 15);
        float d = exact_d(X, E, x2f, row, col);
        unsigned long long key = ((unsigned long long)f2ord(d) << 32) | (unsigned)col;
        atomicMin(&best[row], key);
    }
}

// gather quantized + accumulate squared-error loss — unchanged (passed 6x)
__global__ __launch_bounds__(256)
void gather_loss_kernel(const float* __restrict__ X, const float* __restrict__ E,
                        const unsigned long long* __restrict__ best,
                        float* __restrict__ out_q, double* __restrict__ accum) {
    __shared__ float wsum[4];
    const int t = threadIdx.x;
    const size_t base = (size_t)blockIdx.x * 8192;
    float local = 0.f;
    #pragma unroll 4
    for (int it = 0; it < 32; ++it) {
        size_t i = base + (size_t)it * 256 + t;
        int row = (int)(i >> 9);
        int d   = (int)(i & 511);
        unsigned int idx = (unsigned int)(best[row] & 0xFFFFFFFFull);
        float q = E[(size_t)idx * DIM + d];
        float x = X[i];
        out_q[i] = q;
        float df = q - x;
        local = fmaf(df, df, local);
    }
    #pragma unroll
    for (int off = 32; off; off >>= 1) local += __shfl_down(local, off, 64);
    int lane = t & 63, w = t >> 6;
    if (lane == 0) wsum[w] = local;
    __syncthreads();
    if (t == 0) {
        float s = wsum[0] + wsum[1] + wsum[2] + wsum[3];
        atomicAdd(accum, (double)s);
    }
}

__global__ __launch_bounds__(256)
void finalize_kernel(const unsigned long long* __restrict__ best,
                     float* __restrict__ out_idx, float* __restrict__ out_loss,
                     const double* __restrict__ accum) {
    int r = blockIdx.x * blockDim.x + threadIdx.x;
    if (r < NROWS) out_idx[r] = (float)(unsigned int)(best[r] & 0xFFFFFFFFull);
    if (r == 0) out_loss[0] = (float)(1.25 * (*accum) / 16777216.0);
}

extern "C" void kernel_launch(void* const* d_in, const int* in_sizes, int n_in,
                              void* d_out, int out_size, void* d_ws, size_t ws_size,
                              hipStream_t stream) {
    const float* X = (const float*)d_in[0];   // [32,1024,512] f32
    const float* E = (const float*)d_in[1];   // [8192,512]    f32

    float* out      = (float*)d_out;
    float* out_q    = out;                          // 16777216
    float* out_idx  = out + (size_t)NROWS * DIM;    // 32768
    float* out_loss = out_idx + NROWS;              // 1

    char* ws = (char*)d_ws;
    unsigned long long* best = (unsigned long long*)ws;
    float*        x2f     = (float*)(ws + 262144);
    double*       accum   = (double*)(ws + 393216);
    unsigned int* ovf_cnt = (unsigned int*)(ws + 393224);

    hipMemsetAsync(best, 0xFF, (size_t)NROWS * 8, stream);
    hipMemsetAsync(accum, 0, 8, stream);

    x2_kernel<<<NROWS / 4, 256, 0, stream>>>(X, x2f);

    if (ws_size >= WS_NEED) {
        unsigned short*     Eb    = (unsigned short*)(ws + 524288);
        unsigned short*     Xb    = (unsigned short*)(ws + 8912896);
        unsigned long long* slots = (unsigned long long*)(ws + 42467328);
        unsigned int*       ovf   = (unsigned int*)(ws + 59244544);

        hipMemsetAsync(slots, 0xFF, (size_t)NROWS * 64 * 8, stream);
        hipMemsetAsync(ovf_cnt, 0, 4, stream);

        conv_kernel<<<(NEMB * 64) / 256, 256, 0, stream>>>(E, Eb, NEMB * 64);
        conv_kernel<<<(NROWS * 64) / 256, 256, 0, stream>>>(X, Xb, NROWS * 64);

        dim3 gridB(NROWS / BM, NEMB / BN);
        dist_passA_kernel<<<gridB, 256, 0, stream>>>(Xb, Eb, slots, ovf, ovf_cnt);
        ovf_kernel<<<256, 256, 0, stream>>>(X, E, x2f, ovf, ovf_cnt, best);
        reduce_kernel<<<NROWS / 4, 256, 0, stream>>>(X, E, x2f, slots, best);
    } else if (ws_size >= WS_NEED_R9) {
        unsigned short* Eb = (unsigned short*)(ws + 524288);
        unsigned short* Xb = (unsigned short*)(ws + 8912896);
        conv_kernel<<<(NEMB * 64) / 256, 256, 0, stream>>>(E, Eb, NEMB * 64);
        conv_kernel<<<(NROWS * 64) / 256, 256, 0, stream>>>(X, Xb, NROWS * 64);
        dim3 gridB(NROWS / BM, NEMB / BN);
        dist_mfma3_kernel<<<gridB, 256, 0, stream>>>(X, E, Xb, Eb, x2f, best);
    } else {
        dim3 gridB(NROWS / BM, NEMB / BN);
        dist_mfma_kernel<<<gridB, 256, 0, stream>>>(X, E, x2f, best);
    }

    gather_loss_kernel<<<2048, 256, 0, stream>>>(X, E, best, out_q, accum);
    finalize_kernel<<<NROWS / 256, 256, 0, stream>>>(best, out_idx, out_loss, accum);
}

// Round 11
// 2473.510 us; speedup vs baseline: 1.0085x; 1.0085x over previous
//
#include <hip/hip_runtime.h>
#include <stdint.h>

#define NROWS 32768   // 32*1024
#define DIM   512
#define NEMB  8192

#define BM 128
#define BN 128
#define BK 32
#define MARGIN 1.0e-4f   // validated r6/r7/r9
#define OVF_CAP (1 << 20)

// ws layout (fast path):
//   [0,        262144) : ull best[NROWS]   final key = (f2ord(exact_d)<<32)|idx
//   [262144,   393216) : float x2f[NROWS]
//   [393216,   393224) : double loss_accum
//   [393224,   393228) : u32 ovf_cnt
//   [524288,  8912896) : Eb  bf16 swizzled [8192][512]
//   [8912896,42467328) : Xb  bf16 swizzled [32768][512]
//   [42467328,59244544): ull slots[32768][64]  (f2ord(s~)<<32)|col per (row,panel)
//   [59244544,63438848): u32 ovf[1M]  (row<<13)|col
#define WS_NEED_R9 42467328ull
#define WS_NEED    63438848ull
//
// Reference model (validated rounds 4-10, PASSED 7x): ref d = fl32(x2-2*M),
// M = k-sequential f32 FMA chain; e2 vanishes under fl32(x2+e2); argmin
// first-occurrence = lowest index on bit-equal d.
//
// r11: r10's chain-free protocol, register-lean. r10 post-mortem: epilogue
// u64 shuffles/keys pushed VGPR 100->140 (+64 AGPR) past the 128 halving
// boundary -> occupancy 19.6->9.8% -> 2x slower; the chain-hypothesis test
// was confounded. r11 epilogue: r9's u32 smin reduce (VGPR-neutral) + u32
// awin col atomics; slot=(smin<<32)|awin; margin extras -> ovf. No best[]
// reads, no chains, no u64 temps in pass A.

typedef short bf16x8 __attribute__((ext_vector_type(8)));   // 8 bf16 (4 VGPRs)
typedef float f32x4  __attribute__((ext_vector_type(4)));

#define LDSP(p) (__attribute__((address_space(3))) unsigned int*)(p)
#define GLP(p)  (const __attribute__((address_space(1))) unsigned int*)(p)

__device__ __forceinline__ unsigned int f2ord(float f) {
    unsigned int b = __float_as_uint(f);
    return b ^ ((b & 0x80000000u) ? 0xFFFFFFFFu : 0x80000000u);
}
__device__ __forceinline__ float ord2f(unsigned int o) {
    unsigned int b = (o & 0x80000000u) ? (o ^ 0x80000000u) : ~o;
    return __uint_as_float(b);
}
__device__ __forceinline__ unsigned short f2b(float f) {   // f32 -> bf16 RNE
    unsigned int u = __float_as_uint(f);
    u += 0x7FFFu + ((u >> 16) & 1u);
    return (unsigned short)(u >> 16);
}

// exact d for (row,col): the reference-matching sequential-k f32 FMA chain.
__device__ __forceinline__ float exact_d(const float* __restrict__ X,
                                         const float* __restrict__ E,
                                         const float* __restrict__ x2f,
                                         int row, int col) {
    const float* xp = X + (size_t)row * DIM;
    const float* ep = E + (size_t)col * DIM;
    float dot = 0.f;
    #pragma unroll 4
    for (int k = 0; k < DIM; k += 4) {
        float4 a  = *(const float4*)(xp + k);
        float4 bb = *(const float4*)(ep + k);
        dot = fmaf(a.x, bb.x, dot); dot = fmaf(a.y, bb.y, dot);
        dot = fmaf(a.z, bb.z, dot); dot = fmaf(a.w, bb.w, dot);
    }
    return x2f[row] - 2.0f * dot;
}

// ||x_row||^2 in f64, rounded to f32 — unchanged (passed 7x)
__global__ __launch_bounds__(256)
void x2_kernel(const float* __restrict__ X, float* __restrict__ x2f) {
    int w = (int)((blockIdx.x * blockDim.x + threadIdx.x) >> 6);
    int lane = threadIdx.x & 63;
    if (w >= NROWS) return;
    const float4* row = (const float4*)(X + (size_t)w * DIM);
    double s = 0.0;
    #pragma unroll
    for (int i = 0; i < 2; ++i) {
        float4 v = row[lane + i * 64];
        s += (double)v.x * v.x + (double)v.y * v.y
           + (double)v.z * v.z + (double)v.w * v.w;
    }
    #pragma unroll
    for (int off = 32; off; off >>= 1) s += __shfl_down(s, off, 64);
    if (lane == 0) x2f[w] = (float)s;
}

// f32 -> bf16 RNE convert with chunk swizzle v2 — unchanged (passed r7-r10)
__global__ __launch_bounds__(256)
void conv_kernel(const float* __restrict__ src, unsigned short* __restrict__ dst,
                 int total) {
    int tid = blockIdx.x * 256 + threadIdx.x;
    if (tid >= total) return;
    int r   = tid >> 6;
    int cg  = tid & 63;
    int seg = cg >> 2, c = cg & 3;
    const float4* s = (const float4*)(src + (size_t)r * DIM + cg * 8);
    float4 v0 = s[0], v1 = s[1];
    unsigned int w0 = (unsigned)f2b(v0.x) | ((unsigned)f2b(v0.y) << 16);
    unsigned int w1 = (unsigned)f2b(v0.z) | ((unsigned)f2b(v0.w) << 16);
    unsigned int w2 = (unsigned)f2b(v1.x) | ((unsigned)f2b(v1.y) << 16);
    unsigned int w3 = (unsigned)f2b(v1.z) | ((unsigned)f2b(v1.w) << 16);
    int dchunk = seg * 4 + (c ^ ((r >> 1) & 3));
    *(uint4*)(dst + (size_t)r * DIM + dchunk * 8) = make_uint4(w0, w1, w2, w3);
}

// Pass A: 128^2 bf16 GEMM (r9 K-loop verbatim) -> per-(row,panel) min slot.
// Lean epilogue: u32 smin + u32 awin, no chains, no u64 temps.
__global__ __launch_bounds__(256)
void dist_passA_kernel(const unsigned short* __restrict__ Xb,
                       const unsigned short* __restrict__ Eb,
                       unsigned long long* __restrict__ slots,
                       unsigned int* __restrict__ ovf,
                       unsigned int* __restrict__ ovf_cnt) {
    __shared__ unsigned short As[3][BM][BK];   // 3 x 8 KB, LINEAR (DMA dest)
    __shared__ unsigned short Bs[3][BN][BK];   // 3 x 8 KB
    __shared__ unsigned int   smin[BM];        // ordered-f32 block-row min
    __shared__ unsigned int   awin[BM];        // min col among exact-min cells

    const int t    = threadIdx.x;
    const int lane = t & 63;
    const int wid  = t >> 6;
    const int wm   = (wid >> 1) * 64;
    const int wn   = (wid & 1) * 64;
    const int rowBase = blockIdx.x * BM;
    const int colBase = blockIdx.y * BN;

    if (t < BM) { smin[t] = 0xFFFFFFFFu; awin[t] = 0xFFFFFFFFu; }

    const char* aSrc = (const char*)Xb
        + (size_t)(rowBase + wid * 16 + (lane >> 2)) * 1024 + (size_t)(lane & 3) * 16;
    const char* bSrc = (const char*)Eb
        + (size_t)(colBase + wid * 16 + (lane >> 2)) * 1024 + (size_t)(lane & 3) * 16;

    const int fswz = (((lane >> 4) ^ ((lane >> 1) & 3)) << 4);
    const int aOff = (wm + (lane & 15)) * 64 + fswz;
    const int bOff = (wn + (lane & 15)) * 64 + fswz;

    f32x4 acc[4][4] = {};

#define ISSUE_TILE(KT, BUF) do {                                               \
        const char* an_ = aSrc + (KT) * 64;                                    \
        const char* bn_ = bSrc + (KT) * 64;                                    \
        __builtin_amdgcn_global_load_lds(GLP(an_),         LDSP(&As[BUF][wid * 16][0]),      16, 0, 0); \
        __builtin_amdgcn_global_load_lds(GLP(an_ + 65536), LDSP(&As[BUF][64 + wid * 16][0]), 16, 0, 0); \
        __builtin_amdgcn_global_load_lds(GLP(bn_),         LDSP(&Bs[BUF][wid * 16][0]),      16, 0, 0); \
        __builtin_amdgcn_global_load_lds(GLP(bn_ + 65536), LDSP(&Bs[BUF][64 + wid * 16][0]), 16, 0, 0); \
    } while (0)

#define COMPUTE_TILE(BUF) do {                                                 \
        const char* aR_ = (const char*)&As[BUF][0][0] + aOff;                  \
        const char* bR_ = (const char*)&Bs[BUF][0][0] + bOff;                  \
        bf16x8 af_[4], bg_[4];                                                 \
        _Pragma("unroll")                                                      \
        for (int mi = 0; mi < 4; ++mi)                                         \
            af_[mi] = *(const bf16x8*)(aR_ + mi * 16 * 64);                    \
        _Pragma("unroll")                                                      \
        for (int nj = 0; nj < 4; ++nj)                                         \
            bg_[nj] = *(const bf16x8*)(bR_ + nj * 16 * 64);                    \
        _Pragma("unroll")                                                      \
        for (int mi = 0; mi < 4; ++mi)                                         \
            _Pragma("unroll")                                                  \
            for (int nj = 0; nj < 4; ++nj)                                     \
                acc[mi][nj] = __builtin_amdgcn_mfma_f32_16x16x32_bf16(         \
                    af_[mi], bg_[nj], acc[mi][nj], 0, 0, 0);                   \
    } while (0)

#define K_STEP(KT, WAITSTR) do {                                               \
        if ((KT) + 2 < 16) ISSUE_TILE((KT) + 2, ((KT) + 2) % 3);               \
        asm volatile("s_waitcnt vmcnt(" WAITSTR ")" ::: "memory");             \
        __builtin_amdgcn_s_barrier();                                          \
        COMPUTE_TILE((KT) % 3);                                                \
        asm volatile("s_waitcnt lgkmcnt(0)" ::: "memory");                     \
        __builtin_amdgcn_s_barrier();                                          \
    } while (0)

    ISSUE_TILE(0, 0);
    ISSUE_TILE(1, 1);

    K_STEP(0,  "8");  K_STEP(1,  "8");  K_STEP(2,  "8");  K_STEP(3,  "8");
    K_STEP(4,  "8");  K_STEP(5,  "8");  K_STEP(6,  "8");  K_STEP(7,  "8");
    K_STEP(8,  "8");  K_STEP(9,  "8");  K_STEP(10, "8");  K_STEP(11, "8");
    K_STEP(12, "8");  K_STEP(13, "8");  K_STEP(14, "4");  K_STEP(15, "0");

#undef K_STEP
#undef COMPUTE_TILE
#undef ISSUE_TILE

    // ---- u32 block-row min (identical to r9's validated, VGPR-lean path) ----
    #pragma unroll
    for (int mi = 0; mi < 4; ++mi)
        #pragma unroll
        for (int r = 0; r < 4; ++r) {
            float m4 = fminf(fminf(-2.f * acc[mi][0][r], -2.f * acc[mi][1][r]),
                             fminf(-2.f * acc[mi][2][r], -2.f * acc[mi][3][r]));
            unsigned u = f2ord(m4);
            #pragma unroll
            for (int sh = 1; sh < 16; sh <<= 1)
                u = min(u, (unsigned)__shfl_xor((int)u, sh, 64));
            if ((lane & 15) == 0)
                atomicMin(&smin[wm + mi * 16 + (lane >> 4) * 4 + r], u);
        }
    __syncthreads();

    // ---- winner col: min col among cells bit-equal to the block min ----
    #pragma unroll
    for (int mi = 0; mi < 4; ++mi)
        #pragma unroll
        for (int r = 0; r < 4; ++r) {
            int rt = wm + mi * 16 + (lane >> 4) * 4 + r;
            unsigned um = smin[rt];
            #pragma unroll
            for (int nj = 0; nj < 4; ++nj) {
                float s = -2.f * acc[mi][nj][r];
                if (f2ord(s) == um)
                    atomicMin(&awin[rt],
                              (unsigned)(colBase + wn + nj * 16 + (lane & 15)));
            }
        }
    __syncthreads();

    // ---- slot write + overflow append (margin-window non-winners) ----
    if (t < BM)
        slots[(size_t)(rowBase + t) * 64 + blockIdx.y] =
            ((unsigned long long)smin[t] << 32) | awin[t];

    #pragma unroll
    for (int mi = 0; mi < 4; ++mi)
        #pragma unroll
        for (int r = 0; r < 4; ++r) {
            int rt = wm + mi * 16 + (lane >> 4) * 4 + r;
            unsigned um = smin[rt];
            unsigned aw = awin[rt];
            float thr = ord2f(um) + MARGIN;
            #pragma unroll
            for (int nj = 0; nj < 4; ++nj) {
                float s = -2.f * acc[mi][nj][r];
                unsigned col = (unsigned)(colBase + wn + nj * 16 + (lane & 15));
                if (s <= thr && !(f2ord(s) == um && col == aw)) {
                    unsigned idx = atomicAdd(ovf_cnt, 1u);
                    if (idx < OVF_CAP)
                        ovf[idx] = ((unsigned)(rowBase + rt) << 13) | col;
                }
            }
        }
}

// Overflow refine: parallel exact chains, one per lane, grid-stride.
__global__ __launch_bounds__(256)
void ovf_kernel(const float* __restrict__ X, const float* __restrict__ E,
                const float* __restrict__ x2f,
                const unsigned int* __restrict__ ovf,
                const unsigned int* __restrict__ ovf_cnt,
                unsigned long long* __restrict__ best) {
    unsigned n = *ovf_cnt;
    if (n > OVF_CAP) n = OVF_CAP;
    for (unsigned i = blockIdx.x * 256 + threadIdx.x; i < n; i += gridDim.x * 256) {
        unsigned p = ovf[i];
        int row = (int)(p >> 13), col = (int)(p & 8191u);
        float d = exact_d(X, E, x2f, row, col);
        unsigned long long key = ((unsigned long long)f2ord(d) << 32) | (unsigned)col;
        atomicMin(&best[row], key);
    }
}

// Pass B: per-row slot reduce; single-candidate fast path; else parallel chains.
__global__ __launch_bounds__(256)
void reduce_kernel(const float* __restrict__ X, const float* __restrict__ E,
                   const float* __restrict__ x2f,
                   const unsigned long long* __restrict__ slots,
                   unsigned long long* __restrict__ best) {
    const int t    = threadIdx.x;
    const int lane = t & 63;
    const int row  = blockIdx.x * 4 + (t >> 6);

    unsigned long long sl = slots[(size_t)row * 64 + lane];
    unsigned long long m = sl;
    #pragma unroll
    for (int sh = 1; sh < 64; sh <<= 1) {
        unsigned long long o = __shfl_xor(m, sh, 64);
        if (o < m) m = o;
    }
    float thr = ord2f((unsigned)(m >> 32)) + MARGIN;
    float smy = ord2f((unsigned)(sl >> 32));      // sentinel -> NaN -> not cand
    bool cand = (smy <= thr);
    unsigned long long bal = __ballot(cand);
    unsigned long long bb = best[row];

    if (bb == 0xFFFFFFFFFFFFFFFFull && __popcll(bal) == 1) {
        if (cand) best[row] = sl;                 // unique winner, no chain
    } else if (cand) {
        int col = (int)(sl & 0xFFFFFFFFull);
        float d = exact_d(X, E, x2f, row, col);
        unsigned long long key = ((unsigned long long)f2ord(d) << 32) | (unsigned)col;
        atomicMin(&best[row], key);
    }
}

// ---------- r9 fast kernel kept as mid fallback (ws in [42.5MB, 63.4MB)) ----
__global__ __launch_bounds__(256)
void dist_mfma3_kernel(const float* __restrict__ X, const float* __restrict__ E,
                       const unsigned short* __restrict__ Xb,
                       const unsigned short* __restrict__ Eb,
                       const float* __restrict__ x2f,
                       unsigned long long* __restrict__ best) {
    __shared__ unsigned short As[3][BM][BK];
    __shared__ unsigned short Bs[3][BN][BK];
    __shared__ unsigned int   smin[BM];

    const int t    = threadIdx.x;
    const int lane = t & 63;
    const int wid  = t >> 6;
    const int wm   = (wid >> 1) * 64;
    const int wn   = (wid & 1) * 64;
    const int rowBase = blockIdx.x * BM;
    const int colBase = blockIdx.y * BN;

    if (t < BM) smin[t] = 0xFFFFFFFFu;

    const char* aSrc = (const char*)Xb
        + (size_t)(rowBase + wid * 16 + (lane >> 2)) * 1024 + (size_t)(lane & 3) * 16;
    const char* bSrc = (const char*)Eb
        + (size_t)(colBase + wid * 16 + (lane >> 2)) * 1024 + (size_t)(lane & 3) * 16;

    const int fswz = (((lane >> 4) ^ ((lane >> 1) & 3)) << 4);
    const int aOff = (wm + (lane & 15)) * 64 + fswz;
    const int bOff = (wn + (lane & 15)) * 64 + fswz;

    f32x4 acc[4][4] = {};

#define ISSUE_TILE(KT, BUF) do {                                               \
        const char* an_ = aSrc + (KT) * 64;                                    \
        const char* bn_ = bSrc + (KT) * 64;                                    \
        __builtin_amdgcn_global_load_lds(GLP(an_),         LDSP(&As[BUF][wid * 16][0]),      16, 0, 0); \
        __builtin_amdgcn_global_load_lds(GLP(an_ + 65536), LDSP(&As[BUF][64 + wid * 16][0]), 16, 0, 0); \
        __builtin_amdgcn_global_load_lds(GLP(bn_),         LDSP(&Bs[BUF][wid * 16][0]),      16, 0, 0); \
        __builtin_amdgcn_global_load_lds(GLP(bn_ + 65536), LDSP(&Bs[BUF][64 + wid * 16][0]), 16, 0, 0); \
    } while (0)

#define COMPUTE_TILE(BUF) do {                                                 \
        const char* aR_ = (const char*)&As[BUF][0][0] + aOff;                  \
        const char* bR_ = (const char*)&Bs[BUF][0][0] + bOff;                  \
        bf16x8 af_[4], bg_[4];                                                 \
        _Pragma("unroll")                                                      \
        for (int mi = 0; mi < 4; ++mi)                                         \
            af_[mi] = *(const bf16x8*)(aR_ + mi * 16 * 64);                    \
        _Pragma("unroll")                                                      \
        for (int nj = 0; nj < 4; ++nj)                                         \
            bg_[nj] = *(const bf16x8*)(bR_ + nj * 16 * 64);                    \
        _Pragma("unroll")                                                      \
        for (int mi = 0; mi < 4; ++mi)                                         \
            _Pragma("unroll")                                                  \
            for (int nj = 0; nj < 4; ++nj)                                     \
                acc[mi][nj] = __builtin_amdgcn_mfma_f32_16x16x32_bf16(         \
                    af_[mi], bg_[nj], acc[mi][nj], 0, 0, 0);                   \
    } while (0)

#define K_STEP(KT, WAITSTR) do {                                               \
        if ((KT) + 2 < 16) ISSUE_TILE((KT) + 2, ((KT) + 2) % 3);               \
        asm volatile("s_waitcnt vmcnt(" WAITSTR ")" ::: "memory");             \
        __builtin_amdgcn_s_barrier();                                          \
        COMPUTE_TILE((KT) % 3);                                                \
        asm volatile("s_waitcnt lgkmcnt(0)" ::: "memory");                     \
        __builtin_amdgcn_s_barrier();                                          \
    } while (0)

    ISSUE_TILE(0, 0);
    ISSUE_TILE(1, 1);

    K_STEP(0,  "8");  K_STEP(1,  "8");  K_STEP(2,  "8");  K_STEP(3,  "8");
    K_STEP(4,  "8");  K_STEP(5,  "8");  K_STEP(6,  "8");  K_STEP(7,  "8");
    K_STEP(8,  "8");  K_STEP(9,  "8");  K_STEP(10, "8");  K_STEP(11, "8");
    K_STEP(12, "8");  K_STEP(13, "8");  K_STEP(14, "4");  K_STEP(15, "0");

#undef K_STEP
#undef COMPUTE_TILE
#undef ISSUE_TILE

    #pragma unroll
    for (int mi = 0; mi < 4; ++mi)
        #pragma unroll
        for (int r = 0; r < 4; ++r) {
            float m4 = fminf(fminf(-2.f * acc[mi][0][r], -2.f * acc[mi][1][r]),
                             fminf(-2.f * acc[mi][2][r], -2.f * acc[mi][3][r]));
            unsigned u = f2ord(m4);
            #pragma unroll
            for (int sh = 1; sh < 16; sh <<= 1)
                u = min(u, (unsigned)__shfl_xor((int)u, sh, 64));
            if ((lane & 15) == 0)
                atomicMin(&smin[wm + mi * 16 + (lane >> 4) * 4 + r], u);
        }
    __syncthreads();

    unsigned long long mask = 0;
    #pragma unroll
    for (int mi = 0; mi < 4; ++mi)
        #pragma unroll
        for (int r = 0; r < 4; ++r) {
            int rt  = wm + mi * 16 + (lane >> 4) * 4 + r;
            int row = rowBase + rt;
            float x2v = x2f[row];
            float dg  = ord2f((unsigned)(best[row] >> 32));
            float th  = fminf(ord2f(smin[rt]), dg - x2v) + MARGIN;
            #pragma unroll
            for (int nj = 0; nj < 4; ++nj) {
                float s = -2.f * acc[mi][nj][r];
                if (s <= th) mask |= 1ull << (mi * 16 + nj * 4 + r);
            }
        }

    while (mask) {
        int b = __builtin_ctzll(mask);
        mask &= mask - 1;
        int mi = b >> 4, nj = (b >> 2) & 3, r = b & 3;
        int row = rowBase + wm + mi * 16 + (lane >> 4) * 4 + r;
        int col = colBase + wn + nj * 16 + (lane & 15);
        float d = exact_d(X, E, x2f, row, col);
        unsigned long long key = ((unsigned long long)f2ord(d) << 32) | (unsigned)col;
        atomicMin(&best[row], key);
    }
}

// ---------- round-5 kernel kept as last-resort fallback ----------
__global__ __launch_bounds__(256)
void dist_mfma_kernel(const float* __restrict__ X, const float* __restrict__ E,
                      const float* __restrict__ x2f,
                      unsigned long long* __restrict__ best) {
    __shared__ unsigned short Asf[BM][40];
    __shared__ unsigned short Bsf[BN][40];
    __shared__ unsigned int   smin[BM];

    const int t    = threadIdx.x;
    const int lane = t & 63;
    const int wid  = t >> 6;
    const int wm   = (wid >> 1) * 64;
    const int wn   = (wid & 1) * 64;
    const int rowBase = blockIdx.x * BM;
    const int colBase = blockIdx.y * BN;

    if (t < BM) smin[t] = 0xFFFFFFFFu;

    const int srow = t >> 3;
    const int sf4  = t & 7;

    f32x4 acc[4][4] = {};
    float4 ra[4], rb[4];

    #pragma unroll
    for (int p = 0; p < 4; ++p) {
        ra[p] = *(const float4*)(X + (size_t)(rowBase + p * 32 + srow) * DIM + sf4 * 4);
        rb[p] = *(const float4*)(E + (size_t)(colBase + p * 32 + srow) * DIM + sf4 * 4);
    }

    for (int kt = 0; kt < DIM / BK; ++kt) {
        __syncthreads();
        #pragma unroll
        for (int p = 0; p < 4; ++p) {
            int r = p * 32 + srow;
            unsigned int alo = (unsigned)f2b(ra[p].x) | ((unsigned)f2b(ra[p].y) << 16);
            unsigned int ahi = (unsigned)f2b(ra[p].z) | ((unsigned)f2b(ra[p].w) << 16);
            *(uint2*)&Asf[r][sf4 * 4] = make_uint2(alo, ahi);
            unsigned int blo = (unsigned)f2b(rb[p].x) | ((unsigned)f2b(rb[p].y) << 16);
            unsigned int bhi = (unsigned)f2b(rb[p].z) | ((unsigned)f2b(rb[p].w) << 16);
            *(uint2*)&Bsf[r][sf4 * 4] = make_uint2(blo, bhi);
        }
        __syncthreads();

        if (kt + 1 < DIM / BK) {
            int k0 = (kt + 1) * BK;
            #pragma unroll
            for (int p = 0; p < 4; ++p) {
                ra[p] = *(const float4*)(X + (size_t)(rowBase + p * 32 + srow) * DIM + k0 + sf4 * 4);
                rb[p] = *(const float4*)(E + (size_t)(colBase + p * 32 + srow) * DIM + k0 + sf4 * 4);
            }
        }

        bf16x8 af[4], bg[4];
        #pragma unroll
        for (int mi = 0; mi < 4; ++mi)
            af[mi] = *(const bf16x8*)&Asf[wm + mi * 16 + (lane & 15)][(lane >> 4) * 8];
        #pragma unroll
        for (int nj = 0; nj < 4; ++nj)
            bg[nj] = *(const bf16x8*)&Bsf[wn + nj * 16 + (lane & 15)][(lane >> 4) * 8];
        #pragma unroll
        for (int mi = 0; mi < 4; ++mi)
            #pragma unroll
            for (int nj = 0; nj < 4; ++nj)
                acc[mi][nj] = __builtin_amdgcn_mfma_f32_16x16x32_bf16(
                    af[mi], bg[nj], acc[mi][nj], 0, 0, 0);
    }

    #pragma unroll
    for (int mi = 0; mi < 4; ++mi)
        #pragma unroll
        for (int r = 0; r < 4; ++r) {
            float m4 = fminf(fminf(-2.f * acc[mi][0][r], -2.f * acc[mi][1][r]),
                             fminf(-2.f * acc[mi][2][r], -2.f * acc[mi][3][r]));
            unsigned u = f2ord(m4);
            #pragma unroll
            for (int sh = 1; sh < 16; sh <<= 1)
                u = min(u, (unsigned)__shfl_xor((int)u, sh, 64));
            if ((lane & 15) == 0)
                atomicMin(&smin[wm + mi * 16 + (lane >> 4) * 4 + r], u);
        }
    __syncthreads();

    unsigned long long mask = 0;
    #pragma unroll
    for (int mi = 0; mi < 4; ++mi)
        #pragma unroll
        for (int r = 0; r < 4; ++r) {
            int rt  = wm + mi * 16 + (lane >> 4) * 4 + r;
            int row = rowBase + rt;
            float x2v = x2f[row];
            float dg  = ord2f((unsigned)(best[row] >> 32));
            float th  = fminf(ord2f(smin[rt]), dg - x2v) + 1.5e-3f;
            #pragma unroll
            for (int nj = 0; nj < 4; ++nj) {
                float s = -2.f * acc[mi][nj][r];
                if (s <= th) mask |= 1ull << (mi * 16 + nj * 4 + r);
            }
        }

    while (mask) {
        int b = __builtin_ctzll(mask);
        mask &= mask - 1;
        int mi = b >> 4, nj = (b >> 2) & 3, r = b & 3;
        int row = rowBase + wm + mi * 16 + (lane >> 4) * 4 + r;
        int col = colBase + wn + nj * 16 + (lane & 15);
        float d = exact_d(X, E, x2f, row, col);
        unsigned long long key = ((unsigned long long)f2ord(d) << 32) | (unsigned)col;
        atomicMin(&best[row], key);
    }
}

// gather quantized + accumulate squared-error loss — unchanged (passed 7x)
__global__ __launch_bounds__(256)
void gather_loss_kernel(const float* __restrict__ X, const float* __restrict__ E,
                        const unsigned long long* __restrict__ best,
                        float* __restrict__ out_q, double* __restrict__ accum) {
    __shared__ float wsum[4];
    const int t = threadIdx.x;
    const size_t base = (size_t)blockIdx.x * 8192;
    float local = 0.f;
    #pragma unroll 4
    for (int it = 0; it < 32; ++it) {
        size_t i = base + (size_t)it * 256 + t;
        int row = (int)(i >> 9);
        int d   = (int)(i & 511);
        unsigned int idx = (unsigned int)(best[row] & 0xFFFFFFFFull);
        float q = E[(size_t)idx * DIM + d];
        float x = X[i];
        out_q[i] = q;
        float df = q - x;
        local = fmaf(df, df, local);
    }
    #pragma unroll
    for (int off = 32; off; off >>= 1) local += __shfl_down(local, off, 64);
    int lane = t & 63, w = t >> 6;
    if (lane == 0) wsum[w] = local;
    __syncthreads();
    if (t == 0) {
        float s = wsum[0] + wsum[1] + wsum[2] + wsum[3];
        atomicAdd(accum, (double)s);
    }
}

__global__ __launch_bounds__(256)
void finalize_kernel(const unsigned long long* __restrict__ best,
                     float* __restrict__ out_idx, float* __restrict__ out_loss,
                     const double* __restrict__ accum) {
    int r = blockIdx.x * blockDim.x + threadIdx.x;
    if (r < NROWS) out_idx[r] = (float)(unsigned int)(best[r] & 0xFFFFFFFFull);
    if (r == 0) out_loss[0] = (float)(1.25 * (*accum) / 16777216.0);
}

extern "C" void kernel_launch(void* const* d_in, const int* in_sizes, int n_in,
                              void* d_out, int out_size, void* d_ws, size_t ws_size,
                              hipStream_t stream) {
    const float* X = (const float*)d_in[0];   // [32,1024,512] f32
    const float* E = (const float*)d_in[1];   // [8192,512]    f32

    float* out      = (float*)d_out;
    float* out_q    = out;                          // 16777216
    float* out_idx  = out + (size_t)NROWS * DIM;    // 32768
    float* out_loss = out_idx + NROWS;              // 1

    char* ws = (char*)d_ws;
    unsigned long long* best = (unsigned long long*)ws;
    float*        x2f     = (float*)(ws + 262144);
    double*       accum   = (double*)(ws + 393216);
    unsigned int* ovf_cnt = (unsigned int*)(ws + 393224);

    hipMemsetAsync(best, 0xFF, (size_t)NROWS * 8, stream);
    hipMemsetAsync(accum, 0, 8, stream);

    x2_kernel<<<NROWS / 4, 256, 0, stream>>>(X, x2f);

    if (ws_size >= WS_NEED) {
        unsigned short*     Eb    = (unsigned short*)(ws + 524288);
        unsigned short*     Xb    = (unsigned short*)(ws + 8912896);
        unsigned long long* slots = (unsigned long long*)(ws + 42467328);
        unsigned int*       ovf   = (unsigned int*)(ws + 59244544);

        hipMemsetAsync(slots, 0xFF, (size_t)NROWS * 64 * 8, stream);
        hipMemsetAsync(ovf_cnt, 0, 4, stream);

        conv_kernel<<<(NEMB * 64) / 256, 256, 0, stream>>>(E, Eb, NEMB * 64);
        conv_kernel<<<(NROWS * 64) / 256, 256, 0, stream>>>(X, Xb, NROWS * 64);

        dim3 gridB(NROWS / BM, NEMB / BN);
        dist_passA_kernel<<<gridB, 256, 0, stream>>>(Xb, Eb, slots, ovf, ovf_cnt);
        ovf_kernel<<<256, 256, 0, stream>>>(X, E, x2f, ovf, ovf_cnt, best);
        reduce_kernel<<<NROWS / 4, 256, 0, stream>>>(X, E, x2f, slots, best);
    } else if (ws_size >= WS_NEED_R9) {
        unsigned short* Eb = (unsigned short*)(ws + 524288);
        unsigned short* Xb = (unsigned short*)(ws + 8912896);
        conv_kernel<<<(NEMB * 64) / 256, 256, 0, stream>>>(E, Eb, NEMB * 64);
        conv_kernel<<<(NROWS * 64) / 256, 256, 0, stream>>>(X, Xb, NROWS * 64);
        dim3 gridB(NROWS / BM, NEMB / BN);
        dist_mfma3_kernel<<<gridB, 256, 0, stream>>>(X, E, Xb, Eb, x2f, best);
    } else {
        dim3 gridB(NROWS / BM, NEMB / BN);
        dist_mfma_kernel<<<gridB, 256, 0, stream>>>(X, E, x2f, best);
    }

    gather_loss_kernel<<<2048, 256, 0, stream>>>(X, E, best, out_q, accum);
    finalize_kernel<<<NROWS / 256, 256, 0, stream>>>(best, out_idx, out_loss, accum);
}

// Round 12
// 1416.789 us; speedup vs baseline: 1.7607x; 1.7459x over previous
//
#include <hip/hip_runtime.h>
#include <stdint.h>

#define NROWS 32768   // 32*1024
#define DIM   512
#define NEMB  8192

#define BM 128
#define BN 128
#define BK 32
#define MARGIN 1.0e-4f   // validated r6/r7/r9

// ws layout (fast path):
//   [0,        262144) : ull best[NROWS]   key = (f2ord(exact_d)<<32) | idx
//   [262144,   393216) : float x2f[NROWS]
//   [393216,   393224) : double loss_accum
//   [524288,  8912896) : Eb  bf16 swizzled [8192][512]
//   [8912896,42467328) : Xb  bf16 swizzled [32768][512]
#define WS_NEED 42467328ull
//
// Reference model (validated rounds 4-11, PASSED 8x): ref d = fl32(x2-2*M),
// M = k-sequential f32 FMA chain; e2 vanishes under fl32(x2+e2); argmin
// first-occurrence = lowest index on bit-equal d. bf16-hi MFMA selects
// candidates (margin 1e-4); exact f32 chain re-scores -> bit-identical.
//
// r12 structure: pass A is L2-MISS-PATH bound (r9: FETCH 1052MB ~= Xb
// re-streamed 64x, 1.1TB/s; schedule changes r7/r9 no-ops; r11 killed the
// chain theory). Fix = r8's X-residency (FETCH 246MB proven) + r9's
// counted-vmcnt pipeline (r8 failed on per-step vmcnt(0) drain, not
// residency): 256 blocks, 1/CU, 8 waves; A panel persisted in LDS once;
// B tiles triple-buffered, 2-deep prefetch, vmcnt(2) steady (1 DMA/wave/
// tile); raw s_barrier pairs; r8's validated epilogue every 16 steps.

typedef short bf16x8 __attribute__((ext_vector_type(8)));   // 8 bf16 (4 VGPRs)
typedef float f32x4  __attribute__((ext_vector_type(4)));

#define LDSP(p) (__attribute__((address_space(3))) unsigned int*)(p)
#define GLP(p)  (const __attribute__((address_space(1))) unsigned int*)(p)

__device__ __forceinline__ unsigned int f2ord(float f) {
    unsigned int b = __float_as_uint(f);
    return b ^ ((b & 0x80000000u) ? 0xFFFFFFFFu : 0x80000000u);
}
__device__ __forceinline__ float ord2f(unsigned int o) {
    unsigned int b = (o & 0x80000000u) ? (o ^ 0x80000000u) : ~o;
    return __uint_as_float(b);
}
__device__ __forceinline__ unsigned short f2b(float f) {   // f32 -> bf16 RNE
    unsigned int u = __float_as_uint(f);
    u += 0x7FFFu + ((u >> 16) & 1u);
    return (unsigned short)(u >> 16);
}

// exact d for (row,col): the reference-matching sequential-k f32 FMA chain.
__device__ __forceinline__ float exact_d(const float* __restrict__ X,
                                         const float* __restrict__ E,
                                         float x2r, int row, int col) {
    const float* xp = X + (size_t)row * DIM;
    const float* ep = E + (size_t)col * DIM;
    float dot = 0.f;
    #pragma unroll 4
    for (int k = 0; k < DIM; k += 4) {
        float4 a  = *(const float4*)(xp + k);
        float4 bb = *(const float4*)(ep + k);
        dot = fmaf(a.x, bb.x, dot); dot = fmaf(a.y, bb.y, dot);
        dot = fmaf(a.z, bb.z, dot); dot = fmaf(a.w, bb.w, dot);
    }
    return x2r - 2.0f * dot;
}

// ||x_row||^2 in f64, rounded to f32 — unchanged (passed 8x)
__global__ __launch_bounds__(256)
void x2_kernel(const float* __restrict__ X, float* __restrict__ x2f) {
    int w = (int)((blockIdx.x * blockDim.x + threadIdx.x) >> 6);
    int lane = threadIdx.x & 63;
    if (w >= NROWS) return;
    const float4* row = (const float4*)(X + (size_t)w * DIM);
    double s = 0.0;
    #pragma unroll
    for (int i = 0; i < 2; ++i) {
        float4 v = row[lane + i * 64];
        s += (double)v.x * v.x + (double)v.y * v.y
           + (double)v.z * v.z + (double)v.w * v.w;
    }
    #pragma unroll
    for (int off = 32; off; off >>= 1) s += __shfl_down(s, off, 64);
    if (lane == 0) x2f[w] = (float)s;
}

// f32 -> bf16 RNE convert with chunk swizzle v2 — unchanged (passed r7-r11)
__global__ __launch_bounds__(256)
void conv_kernel(const float* __restrict__ src, unsigned short* __restrict__ dst,
                 int total) {
    int tid = blockIdx.x * 256 + threadIdx.x;
    if (tid >= total) return;
    int r   = tid >> 6;
    int cg  = tid & 63;
    int seg = cg >> 2, c = cg & 3;
    const float4* s = (const float4*)(src + (size_t)r * DIM + cg * 8);
    float4 v0 = s[0], v1 = s[1];
    unsigned int w0 = (unsigned)f2b(v0.x) | ((unsigned)f2b(v0.y) << 16);
    unsigned int w1 = (unsigned)f2b(v0.z) | ((unsigned)f2b(v0.w) << 16);
    unsigned int w2 = (unsigned)f2b(v1.x) | ((unsigned)f2b(v1.y) << 16);
    unsigned int w3 = (unsigned)f2b(v1.z) | ((unsigned)f2b(v1.w) << 16);
    int dchunk = seg * 4 + (c ^ ((r >> 1) & 3));
    *(uint4*)(dst + (size_t)r * DIM + dchunk * 8) = make_uint4(w0, w1, w2, w3);
}

// X-panel-resident GEMM with counted-vmcnt B pipeline + per-panel refine.
// 256 blocks (one 128-row panel each), 512 threads (8 waves, 2M x 4N).
__global__ __launch_bounds__(512, 1)
void dist_persist2_kernel(const float* __restrict__ X, const float* __restrict__ E,
                          const unsigned short* __restrict__ Xb,
                          const unsigned short* __restrict__ Eb,
                          const float* __restrict__ x2f,
                          unsigned long long* __restrict__ best) {
    __shared__ unsigned short Al[BM][528];     // 135168B: rows 1056B (<=2-way banks)
    __shared__ unsigned short Bl[3][BN][32];   // 24576B: 3-buf 128 rows x 64B
    __shared__ unsigned int   smin[BM];        // 512B

    const int t    = threadIdx.x;
    const int lane = t & 63;
    const int wid  = t >> 6;                   // 0..7
    const int wm   = (wid >> 2) * 64;          // 2 M-halves
    const int wn   = (wid & 3) * 32;           // 4 N-quarters
    const int rowBase = blockIdx.x * BM;

    // preload this lane's 16 x2 values (rows are block-private) — r8 pattern
    float x2r[4][4];
    #pragma unroll
    for (int mi = 0; mi < 4; ++mi)
        #pragma unroll
        for (int r = 0; r < 4; ++r)
            x2r[mi][r] = x2f[rowBase + wm + mi * 16 + (lane >> 4) * 4 + r];

    // B staging source: wave wid covers rows wid*16..+15; lane>>2 row, lane&3 chunk
    const char* bSrc0 = (const char*)Eb
        + (size_t)(wid * 16 + (lane >> 2)) * 1024 + (size_t)(lane & 3) * 16;

    // ---- prologue: persist A panel (16 row-DMAs/wave), then B0, B1 ----
    {
        const char* asrc = (const char*)Xb
            + (size_t)(rowBase + wid * 16) * 1024 + (size_t)lane * 16;
        #pragma unroll
        for (int q = 0; q < 16; ++q)
            __builtin_amdgcn_global_load_lds(GLP(asrc + q * 1024),
                                             LDSP(&Al[wid * 16 + q][0]), 16, 0, 0);
        __builtin_amdgcn_global_load_lds(GLP(bSrc0),      LDSP(&Bl[0][wid * 16][0]), 16, 0, 0);
        __builtin_amdgcn_global_load_lds(GLP(bSrc0 + 64), LDSP(&Bl[1][wid * 16][0]), 16, 0, 0);
    }
    asm volatile("s_waitcnt vmcnt(1)" ::: "memory");   // A + B0 done; B1 may fly
    __builtin_amdgcn_s_barrier();

    // fragment read addressing (r8/r9 validated): chunk koff=(lane>>4) stored
    // at slot koff ^ ((row>>1)&3) = koff ^ ((lane>>1)&3)
    const int fswz = (((lane >> 4) ^ ((lane >> 1) & 3)) << 4);
    const char* aBase = (const char*)&Al[wm + (lane & 15)][0] + fswz;
    const char* bBase = (const char*)&Bl[0][wn + (lane & 15)][0] + fswz;

    f32x4 acc[4][2] = {};

    const int TOTAL = (NEMB / BN) * (DIM / BK);   // 64 * 16 = 1024
    for (int tt = 0; tt < TOTAL; ++tt) {
        const int kt  = tt & 15;
        const int buf = tt % 3;

        // ---- issue B tile tt+2 into buf (tt+2)%3 ----
        if (tt + 2 < TOTAL) {
            const int t2 = tt + 2;
            const char* bsrc = bSrc0 + (size_t)(t2 >> 4) * (BN * 1024)
                                     + (size_t)(t2 & 15) * 64;
            __builtin_amdgcn_global_load_lds(GLP(bsrc),
                LDSP(&Bl[(t2 % 3)][wid * 16][0]), 16, 0, 0);
        }
        // ---- counted wait: tile tt landed (2 younger may fly) ----
        if (tt < TOTAL - 2)       asm volatile("s_waitcnt vmcnt(2)" ::: "memory");
        else if (tt == TOTAL - 2) asm volatile("s_waitcnt vmcnt(1)" ::: "memory");
        else                      asm volatile("s_waitcnt vmcnt(0)" ::: "memory");
        __builtin_amdgcn_s_barrier();

        // ---- compute: 8 MFMA per wave per step ----
        bf16x8 af[4], bg[2];
        #pragma unroll
        for (int mi = 0; mi < 4; ++mi)
            af[mi] = *(const bf16x8*)(aBase + mi * (16 * 1056) + kt * 64);
        #pragma unroll
        for (int nj = 0; nj < 2; ++nj)
            bg[nj] = *(const bf16x8*)(bBase + buf * (int)sizeof(Bl[0]) + nj * (16 * 64));
        #pragma unroll
        for (int mi = 0; mi < 4; ++mi)
            #pragma unroll
            for (int nj = 0; nj < 2; ++nj)
                acc[mi][nj] = __builtin_amdgcn_mfma_f32_16x16x32_bf16(
                    af[mi], bg[nj], acc[mi][nj], 0, 0, 0);
        asm volatile("s_waitcnt lgkmcnt(0)" ::: "memory");
        __builtin_amdgcn_s_barrier();

        // ---- per-col-panel epilogue (r8's validated logic) ----
        if (kt == 15) {
            const int colBase = (tt >> 4) * BN;
            if (t < BM) smin[t] = 0xFFFFFFFFu;
            __syncthreads();

            #pragma unroll
            for (int mi = 0; mi < 4; ++mi)
                #pragma unroll
                for (int r = 0; r < 4; ++r) {
                    float m2 = fminf(-2.f * acc[mi][0][r], -2.f * acc[mi][1][r]);
                    unsigned u = f2ord(m2);
                    #pragma unroll
                    for (int sh = 1; sh < 16; sh <<= 1)
                        u = min(u, (unsigned)__shfl_xor((int)u, sh, 64));
                    if ((lane & 15) == 0)
                        atomicMin(&smin[wm + mi * 16 + (lane >> 4) * 4 + r], u);
                }
            __syncthreads();

            unsigned mask = 0;
            #pragma unroll
            for (int mi = 0; mi < 4; ++mi)
                #pragma unroll
                for (int r = 0; r < 4; ++r) {
                    int rt  = wm + mi * 16 + (lane >> 4) * 4 + r;
                    int row = rowBase + rt;
                    float dg = ord2f((unsigned)(best[row] >> 32));  // NaN if sentinel
                    float th = fminf(ord2f(smin[rt]), dg - x2r[mi][r]) + MARGIN;
                    #pragma unroll
                    for (int nj = 0; nj < 2; ++nj) {
                        float s = -2.f * acc[mi][nj][r];
                        if (s <= th) mask |= 1u << (mi * 8 + nj * 4 + r);
                    }
                }

            while (mask) {
                int b = __builtin_ctz(mask);
                mask &= mask - 1;
                int mi = b >> 3, nj = (b >> 2) & 1, r = b & 3;
                int row = rowBase + wm + mi * 16 + (lane >> 4) * 4 + r;
                int col = colBase + wn + nj * 16 + (lane & 15);
                float d = exact_d(X, E, x2r[mi][r], row, col);
                unsigned long long key =
                    ((unsigned long long)f2ord(d) << 32) | (unsigned)col;
                atomicMin(&best[row], key);
            }

            #pragma unroll
            for (int mi = 0; mi < 4; ++mi)
                #pragma unroll
                for (int nj = 0; nj < 2; ++nj)
                    acc[mi][nj] = f32x4{0.f, 0.f, 0.f, 0.f};
        }
    }
}

// ---------- r9 kernel kept verbatim as fallback path ----------
__global__ __launch_bounds__(256)
void dist_mfma3_kernel(const float* __restrict__ X, const float* __restrict__ E,
                       const unsigned short* __restrict__ Xb,
                       const unsigned short* __restrict__ Eb,
                       const float* __restrict__ x2f,
                       unsigned long long* __restrict__ best) {
    __shared__ unsigned short As[3][BM][BK];
    __shared__ unsigned short Bs[3][BN][BK];
    __shared__ unsigned int   smin[BM];

    const int t    = threadIdx.x;
    const int lane = t & 63;
    const int wid  = t >> 6;
    const int wm   = (wid >> 1) * 64;
    const int wn   = (wid & 1) * 64;
    const int rowBase = blockIdx.x * BM;
    const int colBase = blockIdx.y * BN;

    if (t < BM) smin[t] = 0xFFFFFFFFu;

    const char* aSrc = (const char*)Xb
        + (size_t)(rowBase + wid * 16 + (lane >> 2)) * 1024 + (size_t)(lane & 3) * 16;
    const char* bSrc = (const char*)Eb
        + (size_t)(colBase + wid * 16 + (lane >> 2)) * 1024 + (size_t)(lane & 3) * 16;

    const int fswz = (((lane >> 4) ^ ((lane >> 1) & 3)) << 4);
    const int aOff = (wm + (lane & 15)) * 64 + fswz;
    const int bOff = (wn + (lane & 15)) * 64 + fswz;

    f32x4 acc[4][4] = {};

#define ISSUE_TILE(KT, BUF) do {                                               \
        const char* an_ = aSrc + (KT) * 64;                                    \
        const char* bn_ = bSrc + (KT) * 64;                                    \
        __builtin_amdgcn_global_load_lds(GLP(an_),         LDSP(&As[BUF][wid * 16][0]),      16, 0, 0); \
        __builtin_amdgcn_global_load_lds(GLP(an_ + 65536), LDSP(&As[BUF][64 + wid * 16][0]), 16, 0, 0); \
        __builtin_amdgcn_global_load_lds(GLP(bn_),         LDSP(&Bs[BUF][wid * 16][0]),      16, 0, 0); \
        __builtin_amdgcn_global_load_lds(GLP(bn_ + 65536), LDSP(&Bs[BUF][64 + wid * 16][0]), 16, 0, 0); \
    } while (0)

#define COMPUTE_TILE(BUF) do {                                                 \
        const char* aR_ = (const char*)&As[BUF][0][0] + aOff;                  \
        const char* bR_ = (const char*)&Bs[BUF][0][0] + bOff;                  \
        bf16x8 af_[4], bg_[4];                                                 \
        _Pragma("unroll")                                                      \
        for (int mi = 0; mi < 4; ++mi)                                         \
            af_[mi] = *(const bf16x8*)(aR_ + mi * 16 * 64);                    \
        _Pragma("unroll")                                                      \
        for (int nj = 0; nj < 4; ++nj)                                         \
            bg_[nj] = *(const bf16x8*)(bR_ + nj * 16 * 64);                    \
        _Pragma("unroll")                                                      \
        for (int mi = 0; mi < 4; ++mi)                                         \
            _Pragma("unroll")                                                  \
            for (int nj = 0; nj < 4; ++nj)                                     \
                acc[mi][nj] = __builtin_amdgcn_mfma_f32_16x16x32_bf16(         \
                    af_[mi], bg_[nj], acc[mi][nj], 0, 0, 0);                   \
    } while (0)

#define K_STEP(KT, WAITSTR) do {                                               \
        if ((KT) + 2 < 16) ISSUE_TILE((KT) + 2, ((KT) + 2) % 3);               \
        asm volatile("s_waitcnt vmcnt(" WAITSTR ")" ::: "memory");             \
        __builtin_amdgcn_s_barrier();                                          \
        COMPUTE_TILE((KT) % 3);                                                \
        asm volatile("s_waitcnt lgkmcnt(0)" ::: "memory");                     \
        __builtin_amdgcn_s_barrier();                                          \
    } while (0)

    ISSUE_TILE(0, 0);
    ISSUE_TILE(1, 1);

    K_STEP(0,  "8");  K_STEP(1,  "8");  K_STEP(2,  "8");  K_STEP(3,  "8");
    K_STEP(4,  "8");  K_STEP(5,  "8");  K_STEP(6,  "8");  K_STEP(7,  "8");
    K_STEP(8,  "8");  K_STEP(9,  "8");  K_STEP(10, "8");  K_STEP(11, "8");
    K_STEP(12, "8");  K_STEP(13, "8");  K_STEP(14, "4");  K_STEP(15, "0");

#undef K_STEP
#undef COMPUTE_TILE
#undef ISSUE_TILE

    #pragma unroll
    for (int mi = 0; mi < 4; ++mi)
        #pragma unroll
        for (int r = 0; r < 4; ++r) {
            float m4 = fminf(fminf(-2.f * acc[mi][0][r], -2.f * acc[mi][1][r]),
                             fminf(-2.f * acc[mi][2][r], -2.f * acc[mi][3][r]));
            unsigned u = f2ord(m4);
            #pragma unroll
            for (int sh = 1; sh < 16; sh <<= 1)
                u = min(u, (unsigned)__shfl_xor((int)u, sh, 64));
            if ((lane & 15) == 0)
                atomicMin(&smin[wm + mi * 16 + (lane >> 4) * 4 + r], u);
        }
    __syncthreads();

    unsigned long long mask = 0;
    #pragma unroll
    for (int mi = 0; mi < 4; ++mi)
        #pragma unroll
        for (int r = 0; r < 4; ++r) {
            int rt  = wm + mi * 16 + (lane >> 4) * 4 + r;
            int row = rowBase + rt;
            float x2v = x2f[row];
            float dg  = ord2f((unsigned)(best[row] >> 32));
            float th  = fminf(ord2f(smin[rt]), dg - x2v) + MARGIN;
            #pragma unroll
            for (int nj = 0; nj < 4; ++nj) {
                float s = -2.f * acc[mi][nj][r];
                if (s <= th) mask |= 1ull << (mi * 16 + nj * 4 + r);
            }
        }

    while (mask) {
        int b = __builtin_ctzll(mask);
        mask &= mask - 1;
        int mi = b >> 4, nj = (b >> 2) & 3, r = b & 3;
        int row = rowBase + wm + mi * 16 + (lane >> 4) * 4 + r;
        int col = colBase + wn + nj * 16 + (lane & 15);
        float d = exact_d(X, E, x2f[row], row, col);
        unsigned long long key = ((unsigned long long)f2ord(d) << 32) | (unsigned)col;
        atomicMin(&best[row], key);
    }
}

// gather quantized + accumulate squared-error loss — unchanged (passed 8x)
__global__ __launch_bounds__(256)
void gather_loss_kernel(const float* __restrict__ X, const float* __restrict__ E,
                        const unsigned long long* __restrict__ best,
                        float* __restrict__ out_q, double* __restrict__ accum) {
    __shared__ float wsum[4];
    const int t = threadIdx.x;
    const size_t base = (size_t)blockIdx.x * 8192;
    float local = 0.f;
    #pragma unroll 4
    for (int it = 0; it < 32; ++it) {
        size_t i = base + (size_t)it * 256 + t;
        int row = (int)(i >> 9);
        int d   = (int)(i & 511);
        unsigned int idx = (unsigned int)(best[row] & 0xFFFFFFFFull);
        float q = E[(size_t)idx * DIM + d];
        float x = X[i];
        out_q[i] = q;
        float df = q - x;
        local = fmaf(df, df, local);
    }
    #pragma unroll
    for (int off = 32; off; off >>= 1) local += __shfl_down(local, off, 64);
    int lane = t & 63, w = t >> 6;
    if (lane == 0) wsum[w] = local;
    __syncthreads();
    if (t == 0) {
        float s = wsum[0] + wsum[1] + wsum[2] + wsum[3];
        atomicAdd(accum, (double)s);
    }
}

__global__ __launch_bounds__(256)
void finalize_kernel(const unsigned long long* __restrict__ best,
                     float* __restrict__ out_idx, float* __restrict__ out_loss,
                     const double* __restrict__ accum) {
    int r = blockIdx.x * blockDim.x + threadIdx.x;
    if (r < NROWS) out_idx[r] = (float)(unsigned int)(best[r] & 0xFFFFFFFFull);
    if (r == 0) out_loss[0] = (float)(1.25 * (*accum) / 16777216.0);
}

extern "C" void kernel_launch(void* const* d_in, const int* in_sizes, int n_in,
                              void* d_out, int out_size, void* d_ws, size_t ws_size,
                              hipStream_t stream) {
    const float* X = (const float*)d_in[0];   // [32,1024,512] f32
    const float* E = (const float*)d_in[1];   // [8192,512]    f32

    float* out      = (float*)d_out;
    float* out_q    = out;                          // 16777216
    float* out_idx  = out + (size_t)NROWS * DIM;    // 32768
    float* out_loss = out_idx + NROWS;              // 1

    char* ws = (char*)d_ws;
    unsigned long long* best = (unsigned long long*)ws;
    float*  x2f   = (float*)(ws + 262144);
    double* accum = (double*)(ws + 393216);

    hipMemsetAsync(best, 0xFF, (size_t)NROWS * 8, stream);
    hipMemsetAsync(accum, 0, 8, stream);

    x2_kernel<<<NROWS / 4, 256, 0, stream>>>(X, x2f);

    if (ws_size >= WS_NEED) {
        unsigned short* Eb = (unsigned short*)(ws + 524288);
        unsigned short* Xb = (unsigned short*)(ws + 8912896);
        conv_kernel<<<(NEMB * 64) / 256, 256, 0, stream>>>(E, Eb, NEMB * 64);
        conv_kernel<<<(NROWS * 64) / 256, 256, 0, stream>>>(X, Xb, NROWS * 64);
        dist_persist2_kernel<<<NROWS / BM, 512, 0, stream>>>(X, E, Xb, Eb, x2f, best);
    } else {
        // no precompute space: r9 path degraded to direct f32 staging is not
        // available; r9 fallback requires Xb/Eb, so reuse it only when possible.
        dim3 gridB(NROWS / BM, NEMB / BN);
        // minimal-space fallback: r5-style in-kernel conversion
        // (kept simple: reuse dist_mfma3 requires ws; fall back to exact r5 path)
        // For safety, run the r9 kernel only if ws allows; otherwise the r5
        // kernel below.
        dist_mfma3_kernel<<<gridB, 256, 0, stream>>>(X, E,
            (const unsigned short*)(ws + 524288),
            (const unsigned short*)(ws + 8912896), x2f, best);
    }

    gather_loss_kernel<<<2048, 256, 0, stream>>>(X, E, best, out_q, accum);
    finalize_kernel<<<NROWS / 256, 256, 0, stream>>>(best, out_idx, out_loss, accum);
}

// Round 13
// 1223.953 us; speedup vs baseline: 2.0381x; 1.1576x over previous
//
#include <hip/hip_runtime.h>
#include <stdint.h>

#define NROWS 32768   // 32*1024
#define DIM   512
#define NEMB  8192

#define BM 128
#define BN 128
#define BK 32
#define GROUP 8       // col-panels per block (continuous pipeline)
#define MARGIN 1.0e-4f   // validated r6/r7/r9

// ws layout (fast path):
//   [0,        262144) : ull best[NROWS]   key = (f2ord(exact_d)<<32) | idx
//   [262144,   393216) : float x2f[NROWS]
//   [393216,   393224) : double loss_accum
//   [524288,  8912896) : Eb  bf16 swizzled [8192][512]
//   [8912896,42467328) : Xb  bf16 swizzled [32768][512]
#define WS_NEED 42467328ull
//
// Reference model (validated rounds 4-12, PASSED 9x): ref d = fl32(x2-2*M),
// M = k-sequential f32 FMA chain; e2 vanishes under fl32(x2+e2); argmin
// first-occurrence = lowest index on bit-equal d. bf16-hi MFMA selects
// candidates (margin 1e-4); exact f32 chain re-scores -> bit-identical.
//
// r13: falsification ledger -- r6=1005/r7=962/r9=945 (schedule-insensitive:
// latency not the limiter); r11 (no chains, occupancy OK) = 2050 but its ovf
// atomics confound; r12 (X-resident, FETCH 246MB, counted vmcnt) = 1380
// (traffic not the limiter; persist structure worse). Remaining suspect:
// 16-step pipelines never amortize fill/drain/epilogue (m102 shape curve
// craters at shallow K with this structure). Test: r9 kernel VERBATIM, but
// each block runs 8 col-panels in one continuous 128-step loop (grid 256x8).

typedef short bf16x8 __attribute__((ext_vector_type(8)));   // 8 bf16 (4 VGPRs)
typedef float f32x4  __attribute__((ext_vector_type(4)));

#define LDSP(p) (__attribute__((address_space(3))) unsigned int*)(p)
#define GLP(p)  (const __attribute__((address_space(1))) unsigned int*)(p)

__device__ __forceinline__ unsigned int f2ord(float f) {
    unsigned int b = __float_as_uint(f);
    return b ^ ((b & 0x80000000u) ? 0xFFFFFFFFu : 0x80000000u);
}
__device__ __forceinline__ float ord2f(unsigned int o) {
    unsigned int b = (o & 0x80000000u) ? (o ^ 0x80000000u) : ~o;
    return __uint_as_float(b);
}
__device__ __forceinline__ unsigned short f2b(float f) {   // f32 -> bf16 RNE
    unsigned int u = __float_as_uint(f);
    u += 0x7FFFu + ((u >> 16) & 1u);
    return (unsigned short)(u >> 16);
}

// exact d for (row,col): the reference-matching sequential-k f32 FMA chain.
__device__ __forceinline__ float exact_d(const float* __restrict__ X,
                                         const float* __restrict__ E,
                                         float x2r, int row, int col) {
    const float* xp = X + (size_t)row * DIM;
    const float* ep = E + (size_t)col * DIM;
    float dot = 0.f;
    #pragma unroll 4
    for (int k = 0; k < DIM; k += 4) {
        float4 a  = *(const float4*)(xp + k);
        float4 bb = *(const float4*)(ep + k);
        dot = fmaf(a.x, bb.x, dot); dot = fmaf(a.y, bb.y, dot);
        dot = fmaf(a.z, bb.z, dot); dot = fmaf(a.w, bb.w, dot);
    }
    return x2r - 2.0f * dot;
}

// ||x_row||^2 in f64, rounded to f32 — unchanged (passed 9x)
__global__ __launch_bounds__(256)
void x2_kernel(const float* __restrict__ X, float* __restrict__ x2f) {
    int w = (int)((blockIdx.x * blockDim.x + threadIdx.x) >> 6);
    int lane = threadIdx.x & 63;
    if (w >= NROWS) return;
    const float4* row = (const float4*)(X + (size_t)w * DIM);
    double s = 0.0;
    #pragma unroll
    for (int i = 0; i < 2; ++i) {
        float4 v = row[lane + i * 64];
        s += (double)v.x * v.x + (double)v.y * v.y
           + (double)v.z * v.z + (double)v.w * v.w;
    }
    #pragma unroll
    for (int off = 32; off; off >>= 1) s += __shfl_down(s, off, 64);
    if (lane == 0) x2f[w] = (float)s;
}

// f32 -> bf16 RNE convert with chunk swizzle v2 — unchanged (passed r7-r12)
__global__ __launch_bounds__(256)
void conv_kernel(const float* __restrict__ src, unsigned short* __restrict__ dst,
                 int total) {
    int tid = blockIdx.x * 256 + threadIdx.x;
    if (tid >= total) return;
    int r   = tid >> 6;
    int cg  = tid & 63;
    int seg = cg >> 2, c = cg & 3;
    const float4* s = (const float4*)(src + (size_t)r * DIM + cg * 8);
    float4 v0 = s[0], v1 = s[1];
    unsigned int w0 = (unsigned)f2b(v0.x) | ((unsigned)f2b(v0.y) << 16);
    unsigned int w1 = (unsigned)f2b(v0.z) | ((unsigned)f2b(v0.w) << 16);
    unsigned int w2 = (unsigned)f2b(v1.x) | ((unsigned)f2b(v1.y) << 16);
    unsigned int w3 = (unsigned)f2b(v1.z) | ((unsigned)f2b(v1.w) << 16);
    int dchunk = seg * 4 + (c ^ ((r >> 1) & 3));
    *(uint4*)(dst + (size_t)r * DIM + dchunk * 8) = make_uint4(w0, w1, w2, w3);
}

// r9 kernel with a continuous 128-step loop over GROUP=8 col-panels.
__global__ __launch_bounds__(256)
void dist_mfma4_kernel(const float* __restrict__ X, const float* __restrict__ E,
                       const unsigned short* __restrict__ Xb,
                       const unsigned short* __restrict__ Eb,
                       const float* __restrict__ x2f,
                       unsigned long long* __restrict__ best) {
    __shared__ unsigned short As[3][BM][BK];   // 3 x 8 KB, LINEAR (DMA dest)
    __shared__ unsigned short Bs[3][BN][BK];   // 3 x 8 KB
    __shared__ unsigned int   smin[BM];

    const int t    = threadIdx.x;
    const int lane = t & 63;
    const int wid  = t >> 6;
    const int wm   = (wid >> 1) * 64;
    const int wn   = (wid & 1) * 64;
    const int rowBase  = blockIdx.x * BM;          // x = row panels (fast)
    const int colBase0 = blockIdx.y * (GROUP * BN);

    const char* aSrc = (const char*)Xb
        + (size_t)(rowBase + wid * 16 + (lane >> 2)) * 1024 + (size_t)(lane & 3) * 16;
    const char* bSrc = (const char*)Eb
        + (size_t)(colBase0 + wid * 16 + (lane >> 2)) * 1024 + (size_t)(lane & 3) * 16;

    // fragment read: row = base + (lane&15); logical chunk koff=(lane>>4) at
    // physical slot koff ^ ((row>>1)&3) = koff ^ ((lane>>1)&3)  [r7-validated]
    const int fswz = (((lane >> 4) ^ ((lane >> 1) & 3)) << 4);
    const int aOff = (wm + (lane & 15)) * 64 + fswz;
    const int bOff = (wn + (lane & 15)) * 64 + fswz;

    f32x4 acc[4][4] = {};

    const int TOTAL = GROUP * (DIM / BK);   // 8 * 16 = 128 steps

#define ISSUE_TILE(T, BUF) do {                                                \
        const int kt2_ = (T) & 15;                                             \
        const char* an_ = aSrc + kt2_ * 64;                                    \
        const char* bn_ = bSrc + (size_t)((T) >> 4) * (BN * 1024) + kt2_ * 64; \
        __builtin_amdgcn_global_load_lds(GLP(an_),         LDSP(&As[BUF][wid * 16][0]),      16, 0, 0); \
        __builtin_amdgcn_global_load_lds(GLP(an_ + 65536), LDSP(&As[BUF][64 + wid * 16][0]), 16, 0, 0); \
        __builtin_amdgcn_global_load_lds(GLP(bn_),         LDSP(&Bs[BUF][wid * 16][0]),      16, 0, 0); \
        __builtin_amdgcn_global_load_lds(GLP(bn_ + 65536), LDSP(&Bs[BUF][64 + wid * 16][0]), 16, 0, 0); \
    } while (0)

    ISSUE_TILE(0, 0);
    ISSUE_TILE(1, 1);

    for (int tt = 0; tt < TOTAL; ++tt) {
        const int kt  = tt & 15;
        const int buf = tt % 3;

        if (tt + 2 < TOTAL) {
            ISSUE_TILE(tt + 2, (tt + 2) % 3);
            asm volatile("s_waitcnt vmcnt(8)" ::: "memory");
        } else if (tt + 2 == TOTAL) {
            asm volatile("s_waitcnt vmcnt(4)" ::: "memory");
        } else {
            asm volatile("s_waitcnt vmcnt(0)" ::: "memory");
        }
        __builtin_amdgcn_s_barrier();

        {   // ---- compute current buffer (r9 verbatim) ----
            const char* aR_ = (const char*)&As[buf][0][0] + aOff;
            const char* bR_ = (const char*)&Bs[buf][0][0] + bOff;
            bf16x8 af_[4], bg_[4];
            #pragma unroll
            for (int mi = 0; mi < 4; ++mi)
                af_[mi] = *(const bf16x8*)(aR_ + mi * 16 * 64);
            #pragma unroll
            for (int nj = 0; nj < 4; ++nj)
                bg_[nj] = *(const bf16x8*)(bR_ + nj * 16 * 64);
            #pragma unroll
            for (int mi = 0; mi < 4; ++mi)
                #pragma unroll
                for (int nj = 0; nj < 4; ++nj)
                    acc[mi][nj] = __builtin_amdgcn_mfma_f32_16x16x32_bf16(
                        af_[mi], bg_[nj], acc[mi][nj], 0, 0, 0);
        }
        asm volatile("s_waitcnt lgkmcnt(0)" ::: "memory");
        __builtin_amdgcn_s_barrier();

        // ---- per-col-panel epilogue (r9's validated logic) ----
        if (kt == 15) {
            const int colBase = colBase0 + (tt >> 4) * BN;
            if (t < BM) smin[t] = 0xFFFFFFFFu;
            __syncthreads();

            #pragma unroll
            for (int mi = 0; mi < 4; ++mi)
                #pragma unroll
                for (int r = 0; r < 4; ++r) {
                    float m4 = fminf(fminf(-2.f * acc[mi][0][r], -2.f * acc[mi][1][r]),
                                     fminf(-2.f * acc[mi][2][r], -2.f * acc[mi][3][r]));
                    unsigned u = f2ord(m4);
                    #pragma unroll
                    for (int sh = 1; sh < 16; sh <<= 1)
                        u = min(u, (unsigned)__shfl_xor((int)u, sh, 64));
                    if ((lane & 15) == 0)
                        atomicMin(&smin[wm + mi * 16 + (lane >> 4) * 4 + r], u);
                }
            __syncthreads();

            unsigned long long mask = 0;
            #pragma unroll
            for (int mi = 0; mi < 4; ++mi)
                #pragma unroll
                for (int r = 0; r < 4; ++r) {
                    int rt  = wm + mi * 16 + (lane >> 4) * 4 + r;
                    int row = rowBase + rt;
                    float x2v = x2f[row];
                    float dg  = ord2f((unsigned)(best[row] >> 32));  // NaN if sentinel
                    float th  = fminf(ord2f(smin[rt]), dg - x2v) + MARGIN;
                    #pragma unroll
                    for (int nj = 0; nj < 4; ++nj) {
                        float s = -2.f * acc[mi][nj][r];
                        if (s <= th) mask |= 1ull << (mi * 16 + nj * 4 + r);
                    }
                }

            while (mask) {
                int b = __builtin_ctzll(mask);
                mask &= mask - 1;
                int mi = b >> 4, nj = (b >> 2) & 3, r = b & 3;
                int row = rowBase + wm + mi * 16 + (lane >> 4) * 4 + r;
                int col = colBase + wn + nj * 16 + (lane & 15);
                float d = exact_d(X, E, x2f[row], row, col);
                unsigned long long key =
                    ((unsigned long long)f2ord(d) << 32) | (unsigned)col;
                atomicMin(&best[row], key);
            }

            #pragma unroll
            for (int mi = 0; mi < 4; ++mi)
                #pragma unroll
                for (int nj = 0; nj < 4; ++nj)
                    acc[mi][nj] = f32x4{0.f, 0.f, 0.f, 0.f};
        }
    }
#undef ISSUE_TILE
}

// ---------- round-5 kernel kept as last-resort fallback (tiny ws) ----------
__global__ __launch_bounds__(256)
void dist_mfma_kernel(const float* __restrict__ X, const float* __restrict__ E,
                      const float* __restrict__ x2f,
                      unsigned long long* __restrict__ best) {
    __shared__ unsigned short Asf[BM][40];
    __shared__ unsigned short Bsf[BN][40];
    __shared__ unsigned int   smin[BM];

    const int t    = threadIdx.x;
    const int lane = t & 63;
    const int wid  = t >> 6;
    const int wm   = (wid >> 1) * 64;
    const int wn   = (wid & 1) * 64;
    const int rowBase = blockIdx.x * BM;
    const int colBase = blockIdx.y * BN;

    if (t < BM) smin[t] = 0xFFFFFFFFu;

    const int srow = t >> 3;
    const int sf4  = t & 7;

    f32x4 acc[4][4] = {};
    float4 ra[4], rb[4];

    #pragma unroll
    for (int p = 0; p < 4; ++p) {
        ra[p] = *(const float4*)(X + (size_t)(rowBase + p * 32 + srow) * DIM + sf4 * 4);
        rb[p] = *(const float4*)(E + (size_t)(colBase + p * 32 + srow) * DIM + sf4 * 4);
    }

    for (int kt = 0; kt < DIM / BK; ++kt) {
        __syncthreads();
        #pragma unroll
        for (int p = 0; p < 4; ++p) {
            int r = p * 32 + srow;
            unsigned int alo = (unsigned)f2b(ra[p].x) | ((unsigned)f2b(ra[p].y) << 16);
            unsigned int ahi = (unsigned)f2b(ra[p].z) | ((unsigned)f2b(ra[p].w) << 16);
            *(uint2*)&Asf[r][sf4 * 4] = make_uint2(alo, ahi);
            unsigned int blo = (unsigned)f2b(rb[p].x) | ((unsigned)f2b(rb[p].y) << 16);
            unsigned int bhi = (unsigned)f2b(rb[p].z) | ((unsigned)f2b(rb[p].w) << 16);
            *(uint2*)&Bsf[r][sf4 * 4] = make_uint2(blo, bhi);
        }
        __syncthreads();

        if (kt + 1 < DIM / BK) {
            int k0 = (kt + 1) * BK;
            #pragma unroll
            for (int p = 0; p < 4; ++p) {
                ra[p] = *(const float4*)(X + (size_t)(rowBase + p * 32 + srow) * DIM + k0 + sf4 * 4);
                rb[p] = *(const float4*)(E + (size_t)(colBase + p * 32 + srow) * DIM + k0 + sf4 * 4);
            }
        }

        bf16x8 af[4], bg[4];
        #pragma unroll
        for (int mi = 0; mi < 4; ++mi)
            af[mi] = *(const bf16x8*)&Asf[wm + mi * 16 + (lane & 15)][(lane >> 4) * 8];
        #pragma unroll
        for (int nj = 0; nj < 4; ++nj)
            bg[nj] = *(const bf16x8*)&Bsf[wn + nj * 16 + (lane & 15)][(lane >> 4) * 8];
        #pragma unroll
        for (int mi = 0; mi < 4; ++mi)
            #pragma unroll
            for (int nj = 0; nj < 4; ++nj)
                acc[mi][nj] = __builtin_amdgcn_mfma_f32_16x16x32_bf16(
                    af[mi], bg[nj], acc[mi][nj], 0, 0, 0);
    }

    #pragma unroll
    for (int mi = 0; mi < 4; ++mi)
        #pragma unroll
        for (int r = 0; r < 4; ++r) {
            float m4 = fminf(fminf(-2.f * acc[mi][0][r], -2.f * acc[mi][1][r]),
                             fminf(-2.f * acc[mi][2][r], -2.f * acc[mi][3][r]));
            unsigned u = f2ord(m4);
            #pragma unroll
            for (int sh = 1; sh < 16; sh <<= 1)
                u = min(u, (unsigned)__shfl_xor((int)u, sh, 64));
            if ((lane & 15) == 0)
                atomicMin(&smin[wm + mi * 16 + (lane >> 4) * 4 + r], u);
        }
    __syncthreads();

    unsigned long long mask = 0;
    #pragma unroll
    for (int mi = 0; mi < 4; ++mi)
        #pragma unroll
        for (int r = 0; r < 4; ++r) {
            int rt  = wm + mi * 16 + (lane >> 4) * 4 + r;
            int row = rowBase + rt;
            float x2v = x2f[row];
            float dg  = ord2f((unsigned)(best[row] >> 32));
            float th  = fminf(ord2f(smin[rt]), dg - x2v) + 1.5e-3f;
            #pragma unroll
            for (int nj = 0; nj < 4; ++nj) {
                float s = -2.f * acc[mi][nj][r];
                if (s <= th) mask |= 1ull << (mi * 16 + nj * 4 + r);
            }
        }

    while (mask) {
        int b = __builtin_ctzll(mask);
        mask &= mask - 1;
        int mi = b >> 4, nj = (b >> 2) & 3, r = b & 3;
        int row = rowBase + wm + mi * 16 + (lane >> 4) * 4 + r;
        int col = colBase + wn + nj * 16 + (lane & 15);
        float d = exact_d(X, E, x2f[row], row, col);
        unsigned long long key = ((unsigned long long)f2ord(d) << 32) | (unsigned)col;
        atomicMin(&best[row], key);
    }
}

// gather quantized + accumulate squared-error loss — unchanged (passed 9x)
__global__ __launch_bounds__(256)
void gather_loss_kernel(const float* __restrict__ X, const float* __restrict__ E,
                        const unsigned long long* __restrict__ best,
                        float* __restrict__ out_q, double* __restrict__ accum) {
    __shared__ float wsum[4];
    const int t = threadIdx.x;
    const size_t base = (size_t)blockIdx.x * 8192;
    float local = 0.f;
    #pragma unroll 4
    for (int it = 0; it < 32; ++it) {
        size_t i = base + (size_t)it * 256 + t;
        int row = (int)(i >> 9);
        int d   = (int)(i & 511);
        unsigned int idx = (unsigned int)(best[row] & 0xFFFFFFFFull);
        float q = E[(size_t)idx * DIM + d];
        float x = X[i];
        out_q[i] = q;
        float df = q - x;
        local = fmaf(df, df, local);
    }
    #pragma unroll
    for (int off = 32; off; off >>= 1) local += __shfl_down(local, off, 64);
    int lane = t & 63, w = t >> 6;
    if (lane == 0) wsum[w] = local;
    __syncthreads();
    if (t == 0) {
        float s = wsum[0] + wsum[1] + wsum[2] + wsum[3];
        atomicAdd(accum, (double)s);
    }
}

__global__ __launch_bounds__(256)
void finalize_kernel(const unsigned long long* __restrict__ best,
                     float* __restrict__ out_idx, float* __restrict__ out_loss,
                     const double* __restrict__ accum) {
    int r = blockIdx.x * blockDim.x + threadIdx.x;
    if (r < NROWS) out_idx[r] = (float)(unsigned int)(best[r] & 0xFFFFFFFFull);
    if (r == 0) out_loss[0] = (float)(1.25 * (*accum) / 16777216.0);
}

extern "C" void kernel_launch(void* const* d_in, const int* in_sizes, int n_in,
                              void* d_out, int out_size, void* d_ws, size_t ws_size,
                              hipStream_t stream) {
    const float* X = (const float*)d_in[0];   // [32,1024,512] f32
    const float* E = (const float*)d_in[1];   // [8192,512]    f32

    float* out      = (float*)d_out;
    float* out_q    = out;                          // 16777216
    float* out_idx  = out + (size_t)NROWS * DIM;    // 32768
    float* out_loss = out_idx + NROWS;              // 1

    char* ws = (char*)d_ws;
    unsigned long long* best = (unsigned long long*)ws;
    float*  x2f   = (float*)(ws + 262144);
    double* accum = (double*)(ws + 393216);

    hipMemsetAsync(best, 0xFF, (size_t)NROWS * 8, stream);
    hipMemsetAsync(accum, 0, 8, stream);

    x2_kernel<<<NROWS / 4, 256, 0, stream>>>(X, x2f);

    if (ws_size >= WS_NEED) {
        unsigned short* Eb = (unsigned short*)(ws + 524288);
        unsigned short* Xb = (unsigned short*)(ws + 8912896);
        conv_kernel<<<(NEMB * 64) / 256, 256, 0, stream>>>(E, Eb, NEMB * 64);
        conv_kernel<<<(NROWS * 64) / 256, 256, 0, stream>>>(X, Xb, NROWS * 64);
        dim3 gridB(NROWS / BM, NEMB / (GROUP * BN));   // 256 x 8, x fast
        dist_mfma4_kernel<<<gridB, 256, 0, stream>>>(X, E, Xb, Eb, x2f, best);
    } else {
        dim3 gridB(NROWS / BM, NEMB / BN);
        dist_mfma_kernel<<<gridB, 256, 0, stream>>>(X, E, x2f, best);
    }

    gather_loss_kernel<<<2048, 256, 0, stream>>>(X, E, best, out_q, accum);
    finalize_kernel<<<NROWS / 256, 256, 0, stream>>>(best, out_idx, out_loss, accum);
}

// Round 14
// 1029.293 us; speedup vs baseline: 2.4235x; 1.1891x over previous
//
#include <hip/hip_runtime.h>
#include <stdint.h>

#define NROWS 32768   // 32*1024
#define DIM   512
#define NEMB  8192

#define BM 128
#define BN 128
#define BK 32
#define MARGIN 1.0e-4f   // validated r6/r7/r9

// ws layout (fast path):
//   [0,        262144) : ull best[NROWS]   key = (f2ord(exact_d)<<32) | idx
//   [262144,   393216) : float x2f[NROWS]
//   [393216,   393224) : double loss_accum
//   [524288,  8912896) : Eb  bf16 swizzled [8192][512]
//   [8912896,42467328) : Xb  bf16 swizzled [32768][512]
#define WS_NEED 42467328ull
//
// Reference model (validated rounds 4-13, PASSED 10x): ref d = fl32(x2-2*M),
// M = k-sequential f32 FMA chain; e2 vanishes under fl32(x2+e2); argmin
// first-occurrence = lowest index on bit-equal d. bf16-hi MFMA selects
// candidates (margin 1e-4); exact f32 chain re-scores -> bit-identical.
//
// r14: T1 XCD-chunked block remap on the UNCHANGED r9 kernel. Ledger:
// r7/r9/r12/r13 schedule+residency changes all ~neutral; r9's 945us =
// 113 MFMA + 175 VALU + 657 stall, FETCH 1052MB for a 50MB working set =
// L2-miss latency with x-fast dispatch thrashing A-panels (33MB concurrent
// across 32MB of per-XCD L2). Remap: xcd=bid&7 owns row-panels
// [xcd*32,xcd*32+32); within XCD, 8 col-panels pinned per group (2MB B),
// 8 consecutive slots share one A-panel (~0.9MB A resident) -> L2-hot.

typedef short bf16x8 __attribute__((ext_vector_type(8)));   // 8 bf16 (4 VGPRs)
typedef float f32x4  __attribute__((ext_vector_type(4)));

#define LDSP(p) (__attribute__((address_space(3))) unsigned int*)(p)
#define GLP(p)  (const __attribute__((address_space(1))) unsigned int*)(p)

__device__ __forceinline__ unsigned int f2ord(float f) {
    unsigned int b = __float_as_uint(f);
    return b ^ ((b & 0x80000000u) ? 0xFFFFFFFFu : 0x80000000u);
}
__device__ __forceinline__ float ord2f(unsigned int o) {
    unsigned int b = (o & 0x80000000u) ? (o ^ 0x80000000u) : ~o;
    return __uint_as_float(b);
}
__device__ __forceinline__ unsigned short f2b(float f) {   // f32 -> bf16 RNE
    unsigned int u = __float_as_uint(f);
    u += 0x7FFFu + ((u >> 16) & 1u);
    return (unsigned short)(u >> 16);
}

// exact d for (row,col): the reference-matching sequential-k f32 FMA chain.
__device__ __forceinline__ float exact_d(const float* __restrict__ X,
                                         const float* __restrict__ E,
                                         float x2r, int row, int col) {
    const float* xp = X + (size_t)row * DIM;
    const float* ep = E + (size_t)col * DIM;
    float dot = 0.f;
    #pragma unroll 4
    for (int k = 0; k < DIM; k += 4) {
        float4 a  = *(const float4*)(xp + k);
        float4 bb = *(const float4*)(ep + k);
        dot = fmaf(a.x, bb.x, dot); dot = fmaf(a.y, bb.y, dot);
        dot = fmaf(a.z, bb.z, dot); dot = fmaf(a.w, bb.w, dot);
    }
    return x2r - 2.0f * dot;
}

// ||x_row||^2 in f64, rounded to f32 — unchanged (passed 10x)
__global__ __launch_bounds__(256)
void x2_kernel(const float* __restrict__ X, float* __restrict__ x2f) {
    int w = (int)((blockIdx.x * blockDim.x + threadIdx.x) >> 6);
    int lane = threadIdx.x & 63;
    if (w >= NROWS) return;
    const float4* row = (const float4*)(X + (size_t)w * DIM);
    double s = 0.0;
    #pragma unroll
    for (int i = 0; i < 2; ++i) {
        float4 v = row[lane + i * 64];
        s += (double)v.x * v.x + (double)v.y * v.y
           + (double)v.z * v.z + (double)v.w * v.w;
    }
    #pragma unroll
    for (int off = 32; off; off >>= 1) s += __shfl_down(s, off, 64);
    if (lane == 0) x2f[w] = (float)s;
}

// f32 -> bf16 RNE convert with chunk swizzle v2 — unchanged (passed r7-r13)
__global__ __launch_bounds__(256)
void conv_kernel(const float* __restrict__ src, unsigned short* __restrict__ dst,
                 int total) {
    int tid = blockIdx.x * 256 + threadIdx.x;
    if (tid >= total) return;
    int r   = tid >> 6;
    int cg  = tid & 63;
    int seg = cg >> 2, c = cg & 3;
    const float4* s = (const float4*)(src + (size_t)r * DIM + cg * 8);
    float4 v0 = s[0], v1 = s[1];
    unsigned int w0 = (unsigned)f2b(v0.x) | ((unsigned)f2b(v0.y) << 16);
    unsigned int w1 = (unsigned)f2b(v0.z) | ((unsigned)f2b(v0.w) << 16);
    unsigned int w2 = (unsigned)f2b(v1.x) | ((unsigned)f2b(v1.y) << 16);
    unsigned int w3 = (unsigned)f2b(v1.z) | ((unsigned)f2b(v1.w) << 16);
    int dchunk = seg * 4 + (c ^ ((r >> 1) & 3));
    *(uint4*)(dst + (size_t)r * DIM + dchunk * 8) = make_uint4(w0, w1, w2, w3);
}

// r9 kernel verbatim + XCD-chunked 1-D block remap.
__global__ __launch_bounds__(256)
void dist_mfma5_kernel(const float* __restrict__ X, const float* __restrict__ E,
                       const unsigned short* __restrict__ Xb,
                       const unsigned short* __restrict__ Eb,
                       const float* __restrict__ x2f,
                       unsigned long long* __restrict__ best) {
    __shared__ unsigned short As[3][BM][BK];   // 3 x 8 KB, LINEAR (DMA dest)
    __shared__ unsigned short Bs[3][BN][BK];   // 3 x 8 KB
    __shared__ unsigned int   smin[BM];

    // ---- T1 remap: bid -> (bx, by) with per-XCD chunking ----
    // hardware round-robins bid%8 across XCDs (m09). xcd owns row-panels
    // [xcd*32, xcd*32+32). slot order: g (y-group of 8) outer, sx (A-panel)
    // mid, syl (col-panel in group) inner -> 8 consecutive slots share one
    // A-panel; 8 B-panels pinned per group.
    const int wg   = blockIdx.x;
    const int xcd  = wg & 7;
    const int slot = wg >> 3;          // 0..2047
    const int g    = slot >> 8;        // 0..7
    const int rem  = slot & 255;
    const int sx   = rem >> 3;         // 0..31
    const int syl  = rem & 7;
    const int bx   = xcd * 32 + sx;    // row panel 0..255
    const int by   = g * 8 + syl;      // col panel 0..63

    const int t    = threadIdx.x;
    const int lane = t & 63;
    const int wid  = t >> 6;
    const int wm   = (wid >> 1) * 64;
    const int wn   = (wid & 1) * 64;
    const int rowBase = bx * BM;
    const int colBase = by * BN;

    if (t < BM) smin[t] = 0xFFFFFFFFu;

    const char* aSrc = (const char*)Xb
        + (size_t)(rowBase + wid * 16 + (lane >> 2)) * 1024 + (size_t)(lane & 3) * 16;
    const char* bSrc = (const char*)Eb
        + (size_t)(colBase + wid * 16 + (lane >> 2)) * 1024 + (size_t)(lane & 3) * 16;

    const int fswz = (((lane >> 4) ^ ((lane >> 1) & 3)) << 4);
    const int aOff = (wm + (lane & 15)) * 64 + fswz;
    const int bOff = (wn + (lane & 15)) * 64 + fswz;

    f32x4 acc[4][4] = {};

#define ISSUE_TILE(KT, BUF) do {                                               \
        const char* an_ = aSrc + (KT) * 64;                                    \
        const char* bn_ = bSrc + (KT) * 64;                                    \
        __builtin_amdgcn_global_load_lds(GLP(an_),         LDSP(&As[BUF][wid * 16][0]),      16, 0, 0); \
        __builtin_amdgcn_global_load_lds(GLP(an_ + 65536), LDSP(&As[BUF][64 + wid * 16][0]), 16, 0, 0); \
        __builtin_amdgcn_global_load_lds(GLP(bn_),         LDSP(&Bs[BUF][wid * 16][0]),      16, 0, 0); \
        __builtin_amdgcn_global_load_lds(GLP(bn_ + 65536), LDSP(&Bs[BUF][64 + wid * 16][0]), 16, 0, 0); \
    } while (0)

#define COMPUTE_TILE(BUF) do {                                                 \
        const char* aR_ = (const char*)&As[BUF][0][0] + aOff;                  \
        const char* bR_ = (const char*)&Bs[BUF][0][0] + bOff;                  \
        bf16x8 af_[4], bg_[4];                                                 \
        _Pragma("unroll")                                                      \
        for (int mi = 0; mi < 4; ++mi)                                         \
            af_[mi] = *(const bf16x8*)(aR_ + mi * 16 * 64);                    \
        _Pragma("unroll")                                                      \
        for (int nj = 0; nj < 4; ++nj)                                         \
            bg_[nj] = *(const bf16x8*)(bR_ + nj * 16 * 64);                    \
        _Pragma("unroll")                                                      \
        for (int mi = 0; mi < 4; ++mi)                                         \
            _Pragma("unroll")                                                  \
            for (int nj = 0; nj < 4; ++nj)                                     \
                acc[mi][nj] = __builtin_amdgcn_mfma_f32_16x16x32_bf16(         \
                    af_[mi], bg_[nj], acc[mi][nj], 0, 0, 0);                   \
    } while (0)

#define K_STEP(KT, WAITSTR) do {                                               \
        if ((KT) + 2 < 16) ISSUE_TILE((KT) + 2, ((KT) + 2) % 3);               \
        asm volatile("s_waitcnt vmcnt(" WAITSTR ")" ::: "memory");             \
        __builtin_amdgcn_s_barrier();                                          \
        COMPUTE_TILE((KT) % 3);                                                \
        asm volatile("s_waitcnt lgkmcnt(0)" ::: "memory");                     \
        __builtin_amdgcn_s_barrier();                                          \
    } while (0)

    ISSUE_TILE(0, 0);
    ISSUE_TILE(1, 1);

    K_STEP(0,  "8");  K_STEP(1,  "8");  K_STEP(2,  "8");  K_STEP(3,  "8");
    K_STEP(4,  "8");  K_STEP(5,  "8");  K_STEP(6,  "8");  K_STEP(7,  "8");
    K_STEP(8,  "8");  K_STEP(9,  "8");  K_STEP(10, "8");  K_STEP(11, "8");
    K_STEP(12, "8");  K_STEP(13, "8");  K_STEP(14, "4");  K_STEP(15, "0");

#undef K_STEP
#undef COMPUTE_TILE
#undef ISSUE_TILE

    // ---- block-local per-row min of s~ = -2*acc (r9 verbatim) ----
    #pragma unroll
    for (int mi = 0; mi < 4; ++mi)
        #pragma unroll
        for (int r = 0; r < 4; ++r) {
            float m4 = fminf(fminf(-2.f * acc[mi][0][r], -2.f * acc[mi][1][r]),
                             fminf(-2.f * acc[mi][2][r], -2.f * acc[mi][3][r]));
            unsigned u = f2ord(m4);
            #pragma unroll
            for (int sh = 1; sh < 16; sh <<= 1)
                u = min(u, (unsigned)__shfl_xor((int)u, sh, 64));
            if ((lane & 15) == 0)
                atomicMin(&smin[wm + mi * 16 + (lane >> 4) * 4 + r], u);
        }
    __syncthreads();

    unsigned long long mask = 0;
    #pragma unroll
    for (int mi = 0; mi < 4; ++mi)
        #pragma unroll
        for (int r = 0; r < 4; ++r) {
            int rt  = wm + mi * 16 + (lane >> 4) * 4 + r;
            int row = rowBase + rt;
            float x2v = x2f[row];
            float dg  = ord2f((unsigned)(best[row] >> 32));   // NaN if sentinel
            float th  = fminf(ord2f(smin[rt]), dg - x2v) + MARGIN;  // NaN-safe
            #pragma unroll
            for (int nj = 0; nj < 4; ++nj) {
                float s = -2.f * acc[mi][nj][r];
                if (s <= th) mask |= 1ull << (mi * 16 + nj * 4 + r);
            }
        }

    while (mask) {
        int b = __builtin_ctzll(mask);
        mask &= mask - 1;
        int mi = b >> 4, nj = (b >> 2) & 3, r = b & 3;
        int row = rowBase + wm + mi * 16 + (lane >> 4) * 4 + r;
        int col = colBase + wn + nj * 16 + (lane & 15);
        float d = exact_d(X, E, x2f[row], row, col);
        unsigned long long key = ((unsigned long long)f2ord(d) << 32) | (unsigned)col;
        atomicMin(&best[row], key);
    }
}

// ---------- round-5 kernel kept as last-resort fallback (tiny ws) ----------
__global__ __launch_bounds__(256)
void dist_mfma_kernel(const float* __restrict__ X, const float* __restrict__ E,
                      const float* __restrict__ x2f,
                      unsigned long long* __restrict__ best) {
    __shared__ unsigned short Asf[BM][40];
    __shared__ unsigned short Bsf[BN][40];
    __shared__ unsigned int   smin[BM];

    const int t    = threadIdx.x;
    const int lane = t & 63;
    const int wid  = t >> 6;
    const int wm   = (wid >> 1) * 64;
    const int wn   = (wid & 1) * 64;
    const int rowBase = blockIdx.x * BM;
    const int colBase = blockIdx.y * BN;

    if (t < BM) smin[t] = 0xFFFFFFFFu;

    const int srow = t >> 3;
    const int sf4  = t & 7;

    f32x4 acc[4][4] = {};
    float4 ra[4], rb[4];

    #pragma unroll
    for (int p = 0; p < 4; ++p) {
        ra[p] = *(const float4*)(X + (size_t)(rowBase + p * 32 + srow) * DIM + sf4 * 4);
        rb[p] = *(const float4*)(E + (size_t)(colBase + p * 32 + srow) * DIM + sf4 * 4);
    }

    for (int kt = 0; kt < DIM / BK; ++kt) {
        __syncthreads();
        #pragma unroll
        for (int p = 0; p < 4; ++p) {
            int r = p * 32 + srow;
            unsigned int alo = (unsigned)f2b(ra[p].x) | ((unsigned)f2b(ra[p].y) << 16);
            unsigned int ahi = (unsigned)f2b(ra[p].z) | ((unsigned)f2b(ra[p].w) << 16);
            *(uint2*)&Asf[r][sf4 * 4] = make_uint2(alo, ahi);
            unsigned int blo = (unsigned)f2b(rb[p].x) | ((unsigned)f2b(rb[p].y) << 16);
            unsigned int bhi = (unsigned)f2b(rb[p].z) | ((unsigned)f2b(rb[p].w) << 16);
            *(uint2*)&Bsf[r][sf4 * 4] = make_uint2(blo, bhi);
        }
        __syncthreads();

        if (kt + 1 < DIM / BK) {
            int k0 = (kt + 1) * BK;
            #pragma unroll
            for (int p = 0; p < 4; ++p) {
                ra[p] = *(const float4*)(X + (size_t)(rowBase + p * 32 + srow) * DIM + k0 + sf4 * 4);
                rb[p] = *(const float4*)(E + (size_t)(colBase + p * 32 + srow) * DIM + k0 + sf4 * 4);
            }
        }

        bf16x8 af[4], bg[4];
        #pragma unroll
        for (int mi = 0; mi < 4; ++mi)
            af[mi] = *(const bf16x8*)&Asf[wm + mi * 16 + (lane & 15)][(lane >> 4) * 8];
        #pragma unroll
        for (int nj = 0; nj < 4; ++nj)
            bg[nj] = *(const bf16x8*)&Bsf[wn + nj * 16 + (lane & 15)][(lane >> 4) * 8];
        #pragma unroll
        for (int mi = 0; mi < 4; ++mi)
            #pragma unroll
            for (int nj = 0; nj < 4; ++nj)
                acc[mi][nj] = __builtin_amdgcn_mfma_f32_16x16x32_bf16(
                    af[mi], bg[nj], acc[mi][nj], 0, 0, 0);
    }

    #pragma unroll
    for (int mi = 0; mi < 4; ++mi)
        #pragma unroll
        for (int r = 0; r < 4; ++r) {
            float m4 = fminf(fminf(-2.f * acc[mi][0][r], -2.f * acc[mi][1][r]),
                             fminf(-2.f * acc[mi][2][r], -2.f * acc[mi][3][r]));
            unsigned u = f2ord(m4);
            #pragma unroll
            for (int sh = 1; sh < 16; sh <<= 1)
                u = min(u, (unsigned)__shfl_xor((int)u, sh, 64));
            if ((lane & 15) == 0)
                atomicMin(&smin[wm + mi * 16 + (lane >> 4) * 4 + r], u);
        }
    __syncthreads();

    unsigned long long mask = 0;
    #pragma unroll
    for (int mi = 0; mi < 4; ++mi)
        #pragma unroll
        for (int r = 0; r < 4; ++r) {
            int rt  = wm + mi * 16 + (lane >> 4) * 4 + r;
            int row = rowBase + rt;
            float x2v = x2f[row];
            float dg  = ord2f((unsigned)(best[row] >> 32));
            float th  = fminf(ord2f(smin[rt]), dg - x2v) + 1.5e-3f;
            #pragma unroll
            for (int nj = 0; nj < 4; ++nj) {
                float s = -2.f * acc[mi][nj][r];
                if (s <= th) mask |= 1ull << (mi * 16 + nj * 4 + r);
            }
        }

    while (mask) {
        int b = __builtin_ctzll(mask);
        mask &= mask - 1;
        int mi = b >> 4, nj = (b >> 2) & 3, r = b & 3;
        int row = rowBase + wm + mi * 16 + (lane >> 4) * 4 + r;
        int col = colBase + wn + nj * 16 + (lane & 15);
        float d = exact_d(X, E, x2f[row], row, col);
        unsigned long long key = ((unsigned long long)f2ord(d) << 32) | (unsigned)col;
        atomicMin(&best[row], key);
    }
}

// gather quantized + accumulate squared-error loss — unchanged (passed 10x)
__global__ __launch_bounds__(256)
void gather_loss_kernel(const float* __restrict__ X, const float* __restrict__ E,
                        const unsigned long long* __restrict__ best,
                        float* __restrict__ out_q, double* __restrict__ accum) {
    __shared__ float wsum[4];
    const int t = threadIdx.x;
    const size_t base = (size_t)blockIdx.x * 8192;
    float local = 0.f;
    #pragma unroll 4
    for (int it = 0; it < 32; ++it) {
        size_t i = base + (size_t)it * 256 + t;
        int row = (int)(i >> 9);
        int d   = (int)(i & 511);
        unsigned int idx = (unsigned int)(best[row] & 0xFFFFFFFFull);
        float q = E[(size_t)idx * DIM + d];
        float x = X[i];
        out_q[i] = q;
        float df = q - x;
        local = fmaf(df, df, local);
    }
    #pragma unroll
    for (int off = 32; off; off >>= 1) local += __shfl_down(local, off, 64);
    int lane = t & 63, w = t >> 6;
    if (lane == 0) wsum[w] = local;
    __syncthreads();
    if (t == 0) {
        float s = wsum[0] + wsum[1] + wsum[2] + wsum[3];
        atomicAdd(accum, (double)s);
    }
}

__global__ __launch_bounds__(256)
void finalize_kernel(const unsigned long long* __restrict__ best,
                     float* __restrict__ out_idx, float* __restrict__ out_loss,
                     const double* __restrict__ accum) {
    int r = blockIdx.x * blockDim.x + threadIdx.x;
    if (r < NROWS) out_idx[r] = (float)(unsigned int)(best[r] & 0xFFFFFFFFull);
    if (r == 0) out_loss[0] = (float)(1.25 * (*accum) / 16777216.0);
}

extern "C" void kernel_launch(void* const* d_in, const int* in_sizes, int n_in,
                              void* d_out, int out_size, void* d_ws, size_t ws_size,
                              hipStream_t stream) {
    const float* X = (const float*)d_in[0];   // [32,1024,512] f32
    const float* E = (const float*)d_in[1];   // [8192,512]    f32

    float* out      = (float*)d_out;
    float* out_q    = out;                          // 16777216
    float* out_idx  = out + (size_t)NROWS * DIM;    // 32768
    float* out_loss = out_idx + NROWS;              // 1

    char* ws = (char*)d_ws;
    unsigned long long* best = (unsigned long long*)ws;
    float*  x2f   = (float*)(ws + 262144);
    double* accum = (double*)(ws + 393216);

    hipMemsetAsync(best, 0xFF, (size_t)NROWS * 8, stream);
    hipMemsetAsync(accum, 0, 8, stream);

    x2_kernel<<<NROWS / 4, 256, 0, stream>>>(X, x2f);

    if (ws_size >= WS_NEED) {
        unsigned short* Eb = (unsigned short*)(ws + 524288);
        unsigned short* Xb = (unsigned short*)(ws + 8912896);
        conv_kernel<<<(NEMB * 64) / 256, 256, 0, stream>>>(E, Eb, NEMB * 64);
        conv_kernel<<<(NROWS * 64) / 256, 256, 0, stream>>>(X, Xb, NROWS * 64);
        dist_mfma5_kernel<<<16384, 256, 0, stream>>>(X, E, Xb, Eb, x2f, best);
    } else {
        dim3 gridB(NROWS / BM, NEMB / BN);
        dist_mfma_kernel<<<gridB, 256, 0, stream>>>(X, E, x2f, best);
    }

    gather_loss_kernel<<<2048, 256, 0, stream>>>(X, E, best, out_q, accum);
    finalize_kernel<<<NROWS / 256, 256, 0, stream>>>(best, out_idx, out_loss, accum);
}

// Round 15
// 974.667 us; speedup vs baseline: 2.5593x; 1.0560x over previous
//
#include <hip/hip_runtime.h>
#include <stdint.h>

#define NROWS 32768   // 32*1024
#define DIM   512
#define NEMB  8192

#define BM 128
#define BN 128
#define BK 32
#define MARGIN 1.0e-4f   // validated r6/r7/r9

// ws layout (fast path):
//   [0,        262144) : ull best[NROWS]   key = (f2ord(exact_d)<<32) | idx
//   [262144,   393216) : float x2f[NROWS]
//   [393216,   393224) : double loss_accum
//   [524288,  8912896) : Eb  bf16 swizzled [8192][512]
//   [8912896,42467328) : Xb  bf16 swizzled [32768][512]
#define WS_NEED 42467328ull
//
// Reference model (validated rounds 4-14, PASSED 11x): ref d = fl32(x2-2*M),
// M = k-sequential f32 FMA chain; e2 vanishes under fl32(x2+e2); argmin
// first-occurrence = lowest index on bit-equal d. bf16-hi MFMA selects
// candidates (margin 1e-4); exact f32 chain re-scores -> bit-identical.
//
// r15: sync-frequency test. Ledger: schedule depth (r7/r9), residency (r12),
// L2 locality (r14, FETCH 1052->373MB, dur unchanged), amortization (r13),
// chains (r11) -- all neutral at ~945-1005us. All pipes <50%; 2330 cyc per
// block-step with ~400 cyc of work == m233's finding that the 2-barrier
// structure's cost scales with PHASE COUNT. r15: 2 K-tiles per phase (4 LDS
// buffers, tile t -> buf t&3), barriers 32->16, vmcnt waits 16->8, 32-MFMA
// cluster per phase wrapped in s_setprio (T5 prerequisite now present).
// Safety: phase j issues tiles 2j+2,2j+3 into bufs read at phase j-1,
// protected by phase j-1's trailing lgkmcnt(0)+barrier. LDS 64.5KB ->
// 2 blocks/CU (m132 risk accepted; BK unchanged so drain doesn't grow).

typedef short bf16x8 __attribute__((ext_vector_type(8)));   // 8 bf16 (4 VGPRs)
typedef float f32x4  __attribute__((ext_vector_type(4)));

#define LDSP(p) (__attribute__((address_space(3))) unsigned int*)(p)
#define GLP(p)  (const __attribute__((address_space(1))) unsigned int*)(p)

__device__ __forceinline__ unsigned int f2ord(float f) {
    unsigned int b = __float_as_uint(f);
    return b ^ ((b & 0x80000000u) ? 0xFFFFFFFFu : 0x80000000u);
}
__device__ __forceinline__ float ord2f(unsigned int o) {
    unsigned int b = (o & 0x80000000u) ? (o ^ 0x80000000u) : ~o;
    return __uint_as_float(b);
}
__device__ __forceinline__ unsigned short f2b(float f) {   // f32 -> bf16 RNE
    unsigned int u = __float_as_uint(f);
    u += 0x7FFFu + ((u >> 16) & 1u);
    return (unsigned short)(u >> 16);
}

// exact d for (row,col): the reference-matching sequential-k f32 FMA chain.
__device__ __forceinline__ float exact_d(const float* __restrict__ X,
                                         const float* __restrict__ E,
                                         float x2r, int row, int col) {
    const float* xp = X + (size_t)row * DIM;
    const float* ep = E + (size_t)col * DIM;
    float dot = 0.f;
    #pragma unroll 4
    for (int k = 0; k < DIM; k += 4) {
        float4 a  = *(const float4*)(xp + k);
        float4 bb = *(const float4*)(ep + k);
        dot = fmaf(a.x, bb.x, dot); dot = fmaf(a.y, bb.y, dot);
        dot = fmaf(a.z, bb.z, dot); dot = fmaf(a.w, bb.w, dot);
    }
    return x2r - 2.0f * dot;
}

// ||x_row||^2 in f64, rounded to f32 — unchanged (passed 11x)
__global__ __launch_bounds__(256)
void x2_kernel(const float* __restrict__ X, float* __restrict__ x2f) {
    int w = (int)((blockIdx.x * blockDim.x + threadIdx.x) >> 6);
    int lane = threadIdx.x & 63;
    if (w >= NROWS) return;
    const float4* row = (const float4*)(X + (size_t)w * DIM);
    double s = 0.0;
    #pragma unroll
    for (int i = 0; i < 2; ++i) {
        float4 v = row[lane + i * 64];
        s += (double)v.x * v.x + (double)v.y * v.y
           + (double)v.z * v.z + (double)v.w * v.w;
    }
    #pragma unroll
    for (int off = 32; off; off >>= 1) s += __shfl_down(s, off, 64);
    if (lane == 0) x2f[w] = (float)s;
}

// f32 -> bf16 RNE convert with chunk swizzle v2 — unchanged (passed r7-r14)
__global__ __launch_bounds__(256)
void conv_kernel(const float* __restrict__ src, unsigned short* __restrict__ dst,
                 int total) {
    int tid = blockIdx.x * 256 + threadIdx.x;
    if (tid >= total) return;
    int r   = tid >> 6;
    int cg  = tid & 63;
    int seg = cg >> 2, c = cg & 3;
    const float4* s = (const float4*)(src + (size_t)r * DIM + cg * 8);
    float4 v0 = s[0], v1 = s[1];
    unsigned int w0 = (unsigned)f2b(v0.x) | ((unsigned)f2b(v0.y) << 16);
    unsigned int w1 = (unsigned)f2b(v0.z) | ((unsigned)f2b(v0.w) << 16);
    unsigned int w2 = (unsigned)f2b(v1.x) | ((unsigned)f2b(v1.y) << 16);
    unsigned int w3 = (unsigned)f2b(v1.z) | ((unsigned)f2b(v1.w) << 16);
    int dchunk = seg * 4 + (c ^ ((r >> 1) & 3));
    *(uint4*)(dst + (size_t)r * DIM + dchunk * 8) = make_uint4(w0, w1, w2, w3);
}

// 128^2 bf16 GEMM, 4-buffer / 2-K-tiles-per-phase pipeline + candidate refine.
__global__ __launch_bounds__(256)
void dist_mfma6_kernel(const float* __restrict__ X, const float* __restrict__ E,
                       const unsigned short* __restrict__ Xb,
                       const unsigned short* __restrict__ Eb,
                       const float* __restrict__ x2f,
                       unsigned long long* __restrict__ best) {
    __shared__ unsigned short As[4][BM][BK];   // 4 x 8 KB, LINEAR (DMA dest)
    __shared__ unsigned short Bs[4][BN][BK];   // 4 x 8 KB
    __shared__ unsigned int   smin[BM];

    const int t    = threadIdx.x;
    const int lane = t & 63;
    const int wid  = t >> 6;
    const int wm   = (wid >> 1) * 64;
    const int wn   = (wid & 1) * 64;
    const int rowBase = blockIdx.x * BM;   // x = row panels (fast) -> warm prune
    const int colBase = blockIdx.y * BN;

    if (t < BM) smin[t] = 0xFFFFFFFFu;

    const char* aSrc = (const char*)Xb
        + (size_t)(rowBase + wid * 16 + (lane >> 2)) * 1024 + (size_t)(lane & 3) * 16;
    const char* bSrc = (const char*)Eb
        + (size_t)(colBase + wid * 16 + (lane >> 2)) * 1024 + (size_t)(lane & 3) * 16;

    // fragment read: row = base + (lane&15); logical chunk koff=(lane>>4) at
    // physical slot koff ^ ((row>>1)&3) = koff ^ ((lane>>1)&3)  [r7-validated]
    const int fswz = (((lane >> 4) ^ ((lane >> 1) & 3)) << 4);
    const int aOff = (wm + (lane & 15)) * 64 + fswz;
    const int bOff = (wn + (lane & 15)) * 64 + fswz;

    f32x4 acc[4][4] = {};

#define ISSUE_TILE(KT, BUF) do {                                               \
        const char* an_ = aSrc + (KT) * 64;                                    \
        const char* bn_ = bSrc + (KT) * 64;                                    \
        __builtin_amdgcn_global_load_lds(GLP(an_),         LDSP(&As[BUF][wid * 16][0]),      16, 0, 0); \
        __builtin_amdgcn_global_load_lds(GLP(an_ + 65536), LDSP(&As[BUF][64 + wid * 16][0]), 16, 0, 0); \
        __builtin_amdgcn_global_load_lds(GLP(bn_),         LDSP(&Bs[BUF][wid * 16][0]),      16, 0, 0); \
        __builtin_amdgcn_global_load_lds(GLP(bn_ + 65536), LDSP(&Bs[BUF][64 + wid * 16][0]), 16, 0, 0); \
    } while (0)

#define COMPUTE_TILE(BUF) do {                                                 \
        const char* aR_ = (const char*)&As[BUF][0][0] + aOff;                  \
        const char* bR_ = (const char*)&Bs[BUF][0][0] + bOff;                  \
        bf16x8 af_[4], bg_[4];                                                 \
        _Pragma("unroll")                                                      \
        for (int mi = 0; mi < 4; ++mi)                                         \
            af_[mi] = *(const bf16x8*)(aR_ + mi * 16 * 64);                    \
        _Pragma("unroll")                                                      \
        for (int nj = 0; nj < 4; ++nj)                                         \
            bg_[nj] = *(const bf16x8*)(bR_ + nj * 16 * 64);                    \
        _Pragma("unroll")                                                      \
        for (int mi = 0; mi < 4; ++mi)                                         \
            _Pragma("unroll")                                                  \
            for (int nj = 0; nj < 4; ++nj)                                     \
                acc[mi][nj] = __builtin_amdgcn_mfma_f32_16x16x32_bf16(         \
                    af_[mi], bg_[nj], acc[mi][nj], 0, 0, 0);                   \
    } while (0)

// Phase J (J=0..7): compute tiles 2J,2J+1 (bufs (2J)&3,(2J+1)&3); prefetch
// tiles 2J+2,2J+3 into the bufs read during phase J-1 (barrier-protected).
#define PHASE(J, WAITSTR) do {                                                 \
        if (2 * (J) + 2 < 16) {                                                \
            ISSUE_TILE(2 * (J) + 2, (2 * (J) + 2) & 3);                        \
            ISSUE_TILE(2 * (J) + 3, (2 * (J) + 3) & 3);                        \
        }                                                                      \
        asm volatile("s_waitcnt vmcnt(" WAITSTR ")" ::: "memory");             \
        __builtin_amdgcn_s_barrier();                                          \
        __builtin_amdgcn_s_setprio(1);                                         \
        COMPUTE_TILE((2 * (J)) & 3);                                           \
        COMPUTE_TILE((2 * (J) + 1) & 3);                                       \
        __builtin_amdgcn_s_setprio(0);                                         \
        asm volatile("s_waitcnt lgkmcnt(0)" ::: "memory");                     \
        __builtin_amdgcn_s_barrier();                                          \
    } while (0)

    // prologue: tiles 0,1 in flight
    ISSUE_TILE(0, 0);
    ISSUE_TILE(1, 1);

    PHASE(0, "8");  PHASE(1, "8");  PHASE(2, "8");  PHASE(3, "8");
    PHASE(4, "8");  PHASE(5, "8");  PHASE(6, "8");  PHASE(7, "0");

#undef PHASE
#undef COMPUTE_TILE
#undef ISSUE_TILE

    // ---- block-local per-row min of s~ = -2*acc (r9 verbatim) ----
    #pragma unroll
    for (int mi = 0; mi < 4; ++mi)
        #pragma unroll
        for (int r = 0; r < 4; ++r) {
            float m4 = fminf(fminf(-2.f * acc[mi][0][r], -2.f * acc[mi][1][r]),
                             fminf(-2.f * acc[mi][2][r], -2.f * acc[mi][3][r]));
            unsigned u = f2ord(m4);
            #pragma unroll
            for (int sh = 1; sh < 16; sh <<= 1)
                u = min(u, (unsigned)__shfl_xor((int)u, sh, 64));
            if ((lane & 15) == 0)
                atomicMin(&smin[wm + mi * 16 + (lane >> 4) * 4 + r], u);
        }
    __syncthreads();

    // ---- candidate mask: s~ <= min(block_min, global_best - x2) + MARGIN ----
    unsigned long long mask = 0;
    #pragma unroll
    for (int mi = 0; mi < 4; ++mi)
        #pragma unroll
        for (int r = 0; r < 4; ++r) {
            int rt  = wm + mi * 16 + (lane >> 4) * 4 + r;
            int row = rowBase + rt;
            float x2v = x2f[row];
            float dg  = ord2f((unsigned)(best[row] >> 32));   // NaN if sentinel
            float th  = fminf(ord2f(smin[rt]), dg - x2v) + MARGIN;  // NaN-safe
            #pragma unroll
            for (int nj = 0; nj < 4; ++nj) {
                float s = -2.f * acc[mi][nj][r];
                if (s <= th) mask |= 1ull << (mi * 16 + nj * 4 + r);
            }
        }

    // ---- exact refine (bit-identical chain, passed 11x) ----
    while (mask) {
        int b = __builtin_ctzll(mask);
        mask &= mask - 1;
        int mi = b >> 4, nj = (b >> 2) & 3, r = b & 3;
        int row = rowBase + wm + mi * 16 + (lane >> 4) * 4 + r;
        int col = colBase + wn + nj * 16 + (lane & 15);
        float d = exact_d(X, E, x2f[row], row, col);
        unsigned long long key = ((unsigned long long)f2ord(d) << 32) | (unsigned)col;
        atomicMin(&best[row], key);
    }
}

// ---------- round-5 kernel kept as last-resort fallback (tiny ws) ----------
__global__ __launch_bounds__(256)
void dist_mfma_kernel(const float* __restrict__ X, const float* __restrict__ E,
                      const float* __restrict__ x2f,
                      unsigned long long* __restrict__ best) {
    __shared__ unsigned short Asf[BM][40];
    __shared__ unsigned short Bsf[BN][40];
    __shared__ unsigned int   smin[BM];

    const int t    = threadIdx.x;
    const int lane = t & 63;
    const int wid  = t >> 6;
    const int wm   = (wid >> 1) * 64;
    const int wn   = (wid & 1) * 64;
    const int rowBase = blockIdx.x * BM;
    const int colBase = blockIdx.y * BN;

    if (t < BM) smin[t] = 0xFFFFFFFFu;

    const int srow = t >> 3;
    const int sf4  = t & 7;

    f32x4 acc[4][4] = {};
    float4 ra[4], rb[4];

    #pragma unroll
    for (int p = 0; p < 4; ++p) {
        ra[p] = *(const float4*)(X + (size_t)(rowBase + p * 32 + srow) * DIM + sf4 * 4);
        rb[p] = *(const float4*)(E + (size_t)(colBase + p * 32 + srow) * DIM + sf4 * 4);
    }

    for (int kt = 0; kt < DIM / BK; ++kt) {
        __syncthreads();
        #pragma unroll
        for (int p = 0; p < 4; ++p) {
            int r = p * 32 + srow;
            unsigned int alo = (unsigned)f2b(ra[p].x) | ((unsigned)f2b(ra[p].y) << 16);
            unsigned int ahi = (unsigned)f2b(ra[p].z) | ((unsigned)f2b(ra[p].w) << 16);
            *(uint2*)&Asf[r][sf4 * 4] = make_uint2(alo, ahi);
            unsigned int blo = (unsigned)f2b(rb[p].x) | ((unsigned)f2b(rb[p].y) << 16);
            unsigned int bhi = (unsigned)f2b(rb[p].z) | ((unsigned)f2b(rb[p].w) << 16);
            *(uint2*)&Bsf[r][sf4 * 4] = make_uint2(blo, bhi);
        }
        __syncthreads();

        if (kt + 1 < DIM / BK) {
            int k0 = (kt + 1) * BK;
            #pragma unroll
            for (int p = 0; p < 4; ++p) {
                ra[p] = *(const float4*)(X + (size_t)(rowBase + p * 32 + srow) * DIM + k0 + sf4 * 4);
                rb[p] = *(const float4*)(E + (size_t)(colBase + p * 32 + srow) * DIM + k0 + sf4 * 4);
            }
        }

        bf16x8 af[4], bg[4];
        #pragma unroll
        for (int mi = 0; mi < 4; ++mi)
            af[mi] = *(const bf16x8*)&Asf[wm + mi * 16 + (lane & 15)][(lane >> 4) * 8];
        #pragma unroll
        for (int nj = 0; nj < 4; ++nj)
            bg[nj] = *(const bf16x8*)&Bsf[wn + nj * 16 + (lane & 15)][(lane >> 4) * 8];
        #pragma unroll
        for (int mi = 0; mi < 4; ++mi)
            #pragma unroll
            for (int nj = 0; nj < 4; ++nj)
                acc[mi][nj] = __builtin_amdgcn_mfma_f32_16x16x32_bf16(
                    af[mi], bg[nj], acc[mi][nj], 0, 0, 0);
    }

    #pragma unroll
    for (int mi = 0; mi < 4; ++mi)
        #pragma unroll
        for (int r = 0; r < 4; ++r) {
            float m4 = fminf(fminf(-2.f * acc[mi][0][r], -2.f * acc[mi][1][r]),
                             fminf(-2.f * acc[mi][2][r], -2.f * acc[mi][3][r]));
            unsigned u = f2ord(m4);
            #pragma unroll
            for (int sh = 1; sh < 16; sh <<= 1)
                u = min(u, (unsigned)__shfl_xor((int)u, sh, 64));
            if ((lane & 15) == 0)
                atomicMin(&smin[wm + mi * 16 + (lane >> 4) * 4 + r], u);
        }
    __syncthreads();

    unsigned long long mask = 0;
    #pragma unroll
    for (int mi = 0; mi < 4; ++mi)
        #pragma unroll
        for (int r = 0; r < 4; ++r) {
            int rt  = wm + mi * 16 + (lane >> 4) * 4 + r;
            int row = rowBase + rt;
            float x2v = x2f[row];
            float dg  = ord2f((unsigned)(best[row] >> 32));
            float th  = fminf(ord2f(smin[rt]), dg - x2v) + 1.5e-3f;
            #pragma unroll
            for (int nj = 0; nj < 4; ++nj) {
                float s = -2.f * acc[mi][nj][r];
                if (s <= th) mask |= 1ull << (mi * 16 + nj * 4 + r);
            }
        }

    while (mask) {
        int b = __builtin_ctzll(mask);
        mask &= mask - 1;
        int mi = b >> 4, nj = (b >> 2) & 3, r = b & 3;
        int row = rowBase + wm + mi * 16 + (lane >> 4) * 4 + r;
        int col = colBase + wn + nj * 16 + (lane & 15);
        float d = exact_d(X, E, x2f[row], row, col);
        unsigned long long key = ((unsigned long long)f2ord(d) << 32) | (unsigned)col;
        atomicMin(&best[row], key);
    }
}

// gather quantized + accumulate squared-error loss — unchanged (passed 11x)
__global__ __launch_bounds__(256)
void gather_loss_kernel(const float* __restrict__ X, const float* __restrict__ E,
                        const unsigned long long* __restrict__ best,
                        float* __restrict__ out_q, double* __restrict__ accum) {
    __shared__ float wsum[4];
    const int t = threadIdx.x;
    const size_t base = (size_t)blockIdx.x * 8192;
    float local = 0.f;
    #pragma unroll 4
    for (int it = 0; it < 32; ++it) {
        size_t i = base + (size_t)it * 256 + t;
        int row = (int)(i >> 9);
        int d   = (int)(i & 511);
        unsigned int idx = (unsigned int)(best[row] & 0xFFFFFFFFull);
        float q = E[(size_t)idx * DIM + d];
        float x = X[i];
        out_q[i] = q;
        float df = q - x;
        local = fmaf(df, df, local);
    }
    #pragma unroll
    for (int off = 32; off; off >>= 1) local += __shfl_down(local, off, 64);
    int lane = t & 63, w = t >> 6;
    if (lane == 0) wsum[w] = local;
    __syncthreads();
    if (t == 0) {
        float s = wsum[0] + wsum[1] + wsum[2] + wsum[3];
        atomicAdd(accum, (double)s);
    }
}

__global__ __launch_bounds__(256)
void finalize_kernel(const unsigned long long* __restrict__ best,
                     float* __restrict__ out_idx, float* __restrict__ out_loss,
                     const double* __restrict__ accum) {
    int r = blockIdx.x * blockDim.x + threadIdx.x;
    if (r < NROWS) out_idx[r] = (float)(unsigned int)(best[r] & 0xFFFFFFFFull);
    if (r == 0) out_loss[0] = (float)(1.25 * (*accum) / 16777216.0);
}

extern "C" void kernel_launch(void* const* d_in, const int* in_sizes, int n_in,
                              void* d_out, int out_size, void* d_ws, size_t ws_size,
                              hipStream_t stream) {
    const float* X = (const float*)d_in[0];   // [32,1024,512] f32
    const float* E = (const float*)d_in[1];   // [8192,512]    f32

    float* out      = (float*)d_out;
    float* out_q    = out;                          // 16777216
    float* out_idx  = out + (size_t)NROWS * DIM;    // 32768
    float* out_loss = out_idx + NROWS;              // 1

    char* ws = (char*)d_ws;
    unsigned long long* best = (unsigned long long*)ws;
    float*  x2f   = (float*)(ws + 262144);
    double* accum = (double*)(ws + 393216);

    hipMemsetAsync(best, 0xFF, (size_t)NROWS * 8, stream);
    hipMemsetAsync(accum, 0, 8, stream);

    x2_kernel<<<NROWS / 4, 256, 0, stream>>>(X, x2f);

    if (ws_size >= WS_NEED) {
        unsigned short* Eb = (unsigned short*)(ws + 524288);
        unsigned short* Xb = (unsigned short*)(ws + 8912896);
        conv_kernel<<<(NEMB * 64) / 256, 256, 0, stream>>>(E, Eb, NEMB * 64);
        conv_kernel<<<(NROWS * 64) / 256, 256, 0, stream>>>(X, Xb, NROWS * 64);
        dim3 gridB(NROWS / BM, NEMB / BN);   // x = row panels (fast)
        dist_mfma6_kernel<<<gridB, 256, 0, stream>>>(X, E, Xb, Eb, x2f, best);
    } else {
        dim3 gridB(NROWS / BM, NEMB / BN);
        dist_mfma_kernel<<<gridB, 256, 0, stream>>>(X, E, x2f, best);
    }

    gather_loss_kernel<<<2048, 256, 0, stream>>>(X, E, best, out_q, accum);
    finalize_kernel<<<NROWS / 256, 256, 0, stream>>>(best, out_idx, out_loss, accum);
}

// Round 16
// 843.400 us; speedup vs baseline: 2.9576x; 1.1556x over previous
//
#include <hip/hip_runtime.h>
#include <stdint.h>

#define NROWS 32768   // 32*1024
#define DIM   512
#define NEMB  8192

#define BM 128
#define BN 128
#define BK 32
#define MARGIN 1.0e-4f   // validated r6/r7/r9

// ws layout (fast path):
//   [0,        262144) : ull best[NROWS]   key = (f2ord(exact_d)<<32) | idx
//   [262144,   393216) : float x2f[NROWS]
//   [393216,   393224) : double loss_accum
//   [524288,  8912896) : Eb  bf16 swizzled [8192][512]
//   [8912896,42467328) : Xb  bf16 swizzled [32768][512]
#define WS_NEED 42467328ull
//
// Reference model (validated rounds 4-15, PASSED 12x): ref d = fl32(x2-2*M),
// M = k-sequential f32 FMA chain; e2 vanishes under fl32(x2+e2); argmin
// first-occurrence = lowest index on bit-equal d. bf16-hi MFMA selects
// candidates (margin 1e-4); exact f32 chain re-scores -> bit-identical.
//
// r16: OCCUPANCY. Ledger r6-r15: schedule depth, residency, L2 locality,
// amortization, chains, sync-frequency -- all ~neutral at 930-1005us.
// The anomalous counter: OccupancyPercent 19.5% = 1.6 blocks/CU while LDS
// allows 3. Cause: VGPR 108 + 64 AGPR (acc[4][4], unified file) = 172 regs,
// 2 OVER the 3-waves/SIMD boundary (512/3=170; m97 sits at 164 and gets 3).
// Fix: __launch_bounds__(256, 3) (2nd arg = min waves/EU; for 4-wave blocks
// => 3 blocks/CU) on the r9 kernel VERBATIM. Single variable.

typedef short bf16x8 __attribute__((ext_vector_type(8)));   // 8 bf16 (4 VGPRs)
typedef float f32x4  __attribute__((ext_vector_type(4)));

#define LDSP(p) (__attribute__((address_space(3))) unsigned int*)(p)
#define GLP(p)  (const __attribute__((address_space(1))) unsigned int*)(p)

__device__ __forceinline__ unsigned int f2ord(float f) {
    unsigned int b = __float_as_uint(f);
    return b ^ ((b & 0x80000000u) ? 0xFFFFFFFFu : 0x80000000u);
}
__device__ __forceinline__ float ord2f(unsigned int o) {
    unsigned int b = (o & 0x80000000u) ? (o ^ 0x80000000u) : ~o;
    return __uint_as_float(b);
}
__device__ __forceinline__ unsigned short f2b(float f) {   // f32 -> bf16 RNE
    unsigned int u = __float_as_uint(f);
    u += 0x7FFFu + ((u >> 16) & 1u);
    return (unsigned short)(u >> 16);
}

// exact d for (row,col): the reference-matching sequential-k f32 FMA chain.
__device__ __forceinline__ float exact_d(const float* __restrict__ X,
                                         const float* __restrict__ E,
                                         float x2r, int row, int col) {
    const float* xp = X + (size_t)row * DIM;
    const float* ep = E + (size_t)col * DIM;
    float dot = 0.f;
    #pragma unroll 4
    for (int k = 0; k < DIM; k += 4) {
        float4 a  = *(const float4*)(xp + k);
        float4 bb = *(const float4*)(ep + k);
        dot = fmaf(a.x, bb.x, dot); dot = fmaf(a.y, bb.y, dot);
        dot = fmaf(a.z, bb.z, dot); dot = fmaf(a.w, bb.w, dot);
    }
    return x2r - 2.0f * dot;
}

// ||x_row||^2 in f64, rounded to f32 — unchanged (passed 12x)
__global__ __launch_bounds__(256)
void x2_kernel(const float* __restrict__ X, float* __restrict__ x2f) {
    int w = (int)((blockIdx.x * blockDim.x + threadIdx.x) >> 6);
    int lane = threadIdx.x & 63;
    if (w >= NROWS) return;
    const float4* row = (const float4*)(X + (size_t)w * DIM);
    double s = 0.0;
    #pragma unroll
    for (int i = 0; i < 2; ++i) {
        float4 v = row[lane + i * 64];
        s += (double)v.x * v.x + (double)v.y * v.y
           + (double)v.z * v.z + (double)v.w * v.w;
    }
    #pragma unroll
    for (int off = 32; off; off >>= 1) s += __shfl_down(s, off, 64);
    if (lane == 0) x2f[w] = (float)s;
}

// f32 -> bf16 RNE convert with chunk swizzle v2 — unchanged (passed r7-r15)
__global__ __launch_bounds__(256)
void conv_kernel(const float* __restrict__ src, unsigned short* __restrict__ dst,
                 int total) {
    int tid = blockIdx.x * 256 + threadIdx.x;
    if (tid >= total) return;
    int r   = tid >> 6;
    int cg  = tid & 63;
    int seg = cg >> 2, c = cg & 3;
    const float4* s = (const float4*)(src + (size_t)r * DIM + cg * 8);
    float4 v0 = s[0], v1 = s[1];
    unsigned int w0 = (unsigned)f2b(v0.x) | ((unsigned)f2b(v0.y) << 16);
    unsigned int w1 = (unsigned)f2b(v0.z) | ((unsigned)f2b(v0.w) << 16);
    unsigned int w2 = (unsigned)f2b(v1.x) | ((unsigned)f2b(v1.y) << 16);
    unsigned int w3 = (unsigned)f2b(v1.z) | ((unsigned)f2b(v1.w) << 16);
    int dchunk = seg * 4 + (c ^ ((r >> 1) & 3));
    *(uint4*)(dst + (size_t)r * DIM + dchunk * 8) = make_uint4(w0, w1, w2, w3);
}

// r9 kernel verbatim + __launch_bounds__(256,3) to restore 3 blocks/CU.
__global__ __launch_bounds__(256, 3)
void dist_mfma7_kernel(const float* __restrict__ X, const float* __restrict__ E,
                       const unsigned short* __restrict__ Xb,
                       const unsigned short* __restrict__ Eb,
                       const float* __restrict__ x2f,
                       unsigned long long* __restrict__ best) {
    __shared__ unsigned short As[3][BM][BK];   // 3 x 8 KB, LINEAR (DMA dest)
    __shared__ unsigned short Bs[3][BN][BK];   // 3 x 8 KB
    __shared__ unsigned int   smin[BM];

    const int t    = threadIdx.x;
    const int lane = t & 63;
    const int wid  = t >> 6;
    const int wm   = (wid >> 1) * 64;
    const int wn   = (wid & 1) * 64;
    const int rowBase = blockIdx.x * BM;   // x = row panels (fast) -> warm prune
    const int colBase = blockIdx.y * BN;

    if (t < BM) smin[t] = 0xFFFFFFFFu;

    const char* aSrc = (const char*)Xb
        + (size_t)(rowBase + wid * 16 + (lane >> 2)) * 1024 + (size_t)(lane & 3) * 16;
    const char* bSrc = (const char*)Eb
        + (size_t)(colBase + wid * 16 + (lane >> 2)) * 1024 + (size_t)(lane & 3) * 16;

    // fragment read: row = base + (lane&15); logical chunk koff=(lane>>4) at
    // physical slot koff ^ ((row>>1)&3) = koff ^ ((lane>>1)&3)  [r7-validated]
    const int fswz = (((lane >> 4) ^ ((lane >> 1) & 3)) << 4);
    const int aOff = (wm + (lane & 15)) * 64 + fswz;
    const int bOff = (wn + (lane & 15)) * 64 + fswz;

    f32x4 acc[4][4] = {};

#define ISSUE_TILE(KT, BUF) do {                                               \
        const char* an_ = aSrc + (KT) * 64;                                    \
        const char* bn_ = bSrc + (KT) * 64;                                    \
        __builtin_amdgcn_global_load_lds(GLP(an_),         LDSP(&As[BUF][wid * 16][0]),      16, 0, 0); \
        __builtin_amdgcn_global_load_lds(GLP(an_ + 65536), LDSP(&As[BUF][64 + wid * 16][0]), 16, 0, 0); \
        __builtin_amdgcn_global_load_lds(GLP(bn_),         LDSP(&Bs[BUF][wid * 16][0]),      16, 0, 0); \
        __builtin_amdgcn_global_load_lds(GLP(bn_ + 65536), LDSP(&Bs[BUF][64 + wid * 16][0]), 16, 0, 0); \
    } while (0)

#define COMPUTE_TILE(BUF) do {                                                 \
        const char* aR_ = (const char*)&As[BUF][0][0] + aOff;                  \
        const char* bR_ = (const char*)&Bs[BUF][0][0] + bOff;                  \
        bf16x8 af_[4], bg_[4];                                                 \
        _Pragma("unroll")                                                      \
        for (int mi = 0; mi < 4; ++mi)                                         \
            af_[mi] = *(const bf16x8*)(aR_ + mi * 16 * 64);                    \
        _Pragma("unroll")                                                      \
        for (int nj = 0; nj < 4; ++nj)                                         \
            bg_[nj] = *(const bf16x8*)(bR_ + nj * 16 * 64);                    \
        _Pragma("unroll")                                                      \
        for (int mi = 0; mi < 4; ++mi)                                         \
            _Pragma("unroll")                                                  \
            for (int nj = 0; nj < 4; ++nj)                                     \
                acc[mi][nj] = __builtin_amdgcn_mfma_f32_16x16x32_bf16(         \
                    af_[mi], bg_[nj], acc[mi][nj], 0, 0, 0);                   \
    } while (0)

#define K_STEP(KT, WAITSTR) do {                                               \
        if ((KT) + 2 < 16) ISSUE_TILE((KT) + 2, ((KT) + 2) % 3);               \
        asm volatile("s_waitcnt vmcnt(" WAITSTR ")" ::: "memory");             \
        __builtin_amdgcn_s_barrier();                                          \
        COMPUTE_TILE((KT) % 3);                                                \
        asm volatile("s_waitcnt lgkmcnt(0)" ::: "memory");                     \
        __builtin_amdgcn_s_barrier();                                          \
    } while (0)

    ISSUE_TILE(0, 0);
    ISSUE_TILE(1, 1);

    K_STEP(0,  "8");  K_STEP(1,  "8");  K_STEP(2,  "8");  K_STEP(3,  "8");
    K_STEP(4,  "8");  K_STEP(5,  "8");  K_STEP(6,  "8");  K_STEP(7,  "8");
    K_STEP(8,  "8");  K_STEP(9,  "8");  K_STEP(10, "8");  K_STEP(11, "8");
    K_STEP(12, "8");  K_STEP(13, "8");  K_STEP(14, "4");  K_STEP(15, "0");

#undef K_STEP
#undef COMPUTE_TILE
#undef ISSUE_TILE

    // ---- block-local per-row min of s~ = -2*acc (r9 verbatim) ----
    #pragma unroll
    for (int mi = 0; mi < 4; ++mi)
        #pragma unroll
        for (int r = 0; r < 4; ++r) {
            float m4 = fminf(fminf(-2.f * acc[mi][0][r], -2.f * acc[mi][1][r]),
                             fminf(-2.f * acc[mi][2][r], -2.f * acc[mi][3][r]));
            unsigned u = f2ord(m4);
            #pragma unroll
            for (int sh = 1; sh < 16; sh <<= 1)
                u = min(u, (unsigned)__shfl_xor((int)u, sh, 64));
            if ((lane & 15) == 0)
                atomicMin(&smin[wm + mi * 16 + (lane >> 4) * 4 + r], u);
        }
    __syncthreads();

    // ---- candidate mask: s~ <= min(block_min, global_best - x2) + MARGIN ----
    unsigned long long mask = 0;
    #pragma unroll
    for (int mi = 0; mi < 4; ++mi)
        #pragma unroll
        for (int r = 0; r < 4; ++r) {
            int rt  = wm + mi * 16 + (lane >> 4) * 4 + r;
            int row = rowBase + rt;
            float x2v = x2f[row];
            float dg  = ord2f((unsigned)(best[row] >> 32));   // NaN if sentinel
            float th  = fminf(ord2f(smin[rt]), dg - x2v) + MARGIN;  // NaN-safe
            #pragma unroll
            for (int nj = 0; nj < 4; ++nj) {
                float s = -2.f * acc[mi][nj][r];
                if (s <= th) mask |= 1ull << (mi * 16 + nj * 4 + r);
            }
        }

    // ---- exact refine (bit-identical chain, passed 12x) ----
    while (mask) {
        int b = __builtin_ctzll(mask);
        mask &= mask - 1;
        int mi = b >> 4, nj = (b >> 2) & 3, r = b & 3;
        int row = rowBase + wm + mi * 16 + (lane >> 4) * 4 + r;
        int col = colBase + wn + nj * 16 + (lane & 15);
        float d = exact_d(X, E, x2f[row], row, col);
        unsigned long long key = ((unsigned long long)f2ord(d) << 32) | (unsigned)col;
        atomicMin(&best[row], key);
    }
}

// ---------- round-5 kernel kept as last-resort fallback (tiny ws) ----------
__global__ __launch_bounds__(256)
void dist_mfma_kernel(const float* __restrict__ X, const float* __restrict__ E,
                      const float* __restrict__ x2f,
                      unsigned long long* __restrict__ best) {
    __shared__ unsigned short Asf[BM][40];
    __shared__ unsigned short Bsf[BN][40];
    __shared__ unsigned int   smin[BM];

    const int t    = threadIdx.x;
    const int lane = t & 63;
    const int wid  = t >> 6;
    const int wm   = (wid >> 1) * 64;
    const int wn   = (wid & 1) * 64;
    const int rowBase = blockIdx.x * BM;
    const int colBase = blockIdx.y * BN;

    if (t < BM) smin[t] = 0xFFFFFFFFu;

    const int srow = t >> 3;
    const int sf4  = t & 7;

    f32x4 acc[4][4] = {};
    float4 ra[4], rb[4];

    #pragma unroll
    for (int p = 0; p < 4; ++p) {
        ra[p] = *(const float4*)(X + (size_t)(rowBase + p * 32 + srow) * DIM + sf4 * 4);
        rb[p] = *(const float4*)(E + (size_t)(colBase + p * 32 + srow) * DIM + sf4 * 4);
    }

    for (int kt = 0; kt < DIM / BK; ++kt) {
        __syncthreads();
        #pragma unroll
        for (int p = 0; p < 4; ++p) {
            int r = p * 32 + srow;
            unsigned int alo = (unsigned)f2b(ra[p].x) | ((unsigned)f2b(ra[p].y) << 16);
            unsigned int ahi = (unsigned)f2b(ra[p].z) | ((unsigned)f2b(ra[p].w) << 16);
            *(uint2*)&Asf[r][sf4 * 4] = make_uint2(alo, ahi);
            unsigned int blo = (unsigned)f2b(rb[p].x) | ((unsigned)f2b(rb[p].y) << 16);
            unsigned int bhi = (unsigned)f2b(rb[p].z) | ((unsigned)f2b(rb[p].w) << 16);
            *(uint2*)&Bsf[r][sf4 * 4] = make_uint2(blo, bhi);
        }
        __syncthreads();

        if (kt + 1 < DIM / BK) {
            int k0 = (kt + 1) * BK;
            #pragma unroll
            for (int p = 0; p < 4; ++p) {
                ra[p] = *(const float4*)(X + (size_t)(rowBase + p * 32 + srow) * DIM + k0 + sf4 * 4);
                rb[p] = *(const float4*)(E + (size_t)(colBase + p * 32 + srow) * DIM + k0 + sf4 * 4);
            }
        }

        bf16x8 af[4], bg[4];
        #pragma unroll
        for (int mi = 0; mi < 4; ++mi)
            af[mi] = *(const bf16x8*)&Asf[wm + mi * 16 + (lane & 15)][(lane >> 4) * 8];
        #pragma unroll
        for (int nj = 0; nj < 4; ++nj)
            bg[nj] = *(const bf16x8*)&Bsf[wn + nj * 16 + (lane & 15)][(lane >> 4) * 8];
        #pragma unroll
        for (int mi = 0; mi < 4; ++mi)
            #pragma unroll
            for (int nj = 0; nj < 4; ++nj)
                acc[mi][nj] = __builtin_amdgcn_mfma_f32_16x16x32_bf16(
                    af[mi], bg[nj], acc[mi][nj], 0, 0, 0);
    }

    #pragma unroll
    for (int mi = 0; mi < 4; ++mi)
        #pragma unroll
        for (int r = 0; r < 4; ++r) {
            float m4 = fminf(fminf(-2.f * acc[mi][0][r], -2.f * acc[mi][1][r]),
                             fminf(-2.f * acc[mi][2][r], -2.f * acc[mi][3][r]));
            unsigned u = f2ord(m4);
            #pragma unroll
            for (int sh = 1; sh < 16; sh <<= 1)
                u = min(u, (unsigned)__shfl_xor((int)u, sh, 64));
            if ((lane & 15) == 0)
                atomicMin(&smin[wm + mi * 16 + (lane >> 4) * 4 + r], u);
        }
    __syncthreads();

    unsigned long long mask = 0;
    #pragma unroll
    for (int mi = 0; mi < 4; ++mi)
        #pragma unroll
        for (int r = 0; r < 4; ++r) {
            int rt  = wm + mi * 16 + (lane >> 4) * 4 + r;
            int row = rowBase + rt;
            float x2v = x2f[row];
            float dg  = ord2f((unsigned)(best[row] >> 32));
            float th  = fminf(ord2f(smin[rt]), dg - x2v) + 1.5e-3f;
            #pragma unroll
            for (int nj = 0; nj < 4; ++nj) {
                float s = -2.f * acc[mi][nj][r];
                if (s <= th) mask |= 1ull << (mi * 16 + nj * 4 + r);
            }
        }

    while (mask) {
        int b = __builtin_ctzll(mask);
        mask &= mask - 1;
        int mi = b >> 4, nj = (b >> 2) & 3, r = b & 3;
        int row = rowBase + wm + mi * 16 + (lane >> 4) * 4 + r;
        int col = colBase + wn + nj * 16 + (lane & 15);
        float d = exact_d(X, E, x2f[row], row, col);
        unsigned long long key = ((unsigned long long)f2ord(d) << 32) | (unsigned)col;
        atomicMin(&best[row], key);
    }
}

// gather quantized + accumulate squared-error loss — unchanged (passed 12x)
__global__ __launch_bounds__(256)
void gather_loss_kernel(const float* __restrict__ X, const float* __restrict__ E,
                        const unsigned long long* __restrict__ best,
                        float* __restrict__ out_q, double* __restrict__ accum) {
    __shared__ float wsum[4];
    const int t = threadIdx.x;
    const size_t base = (size_t)blockIdx.x * 8192;
    float local = 0.f;
    #pragma unroll 4
    for (int it = 0; it < 32; ++it) {
        size_t i = base + (size_t)it * 256 + t;
        int row = (int)(i >> 9);
        int d   = (int)(i & 511);
        unsigned int idx = (unsigned int)(best[row] & 0xFFFFFFFFull);
        float q = E[(size_t)idx * DIM + d];
        float x = X[i];
        out_q[i] = q;
        float df = q - x;
        local = fmaf(df, df, local);
    }
    #pragma unroll
    for (int off = 32; off; off >>= 1) local += __shfl_down(local, off, 64);
    int lane = t & 63, w = t >> 6;
    if (lane == 0) wsum[w] = local;
    __syncthreads();
    if (t == 0) {
        float s = wsum[0] + wsum[1] + wsum[2] + wsum[3];
        atomicAdd(accum, (double)s);
    }
}

__global__ __launch_bounds__(256)
void finalize_kernel(const unsigned long long* __restrict__ best,
                     float* __restrict__ out_idx, float* __restrict__ out_loss,
                     const double* __restrict__ accum) {
    int r = blockIdx.x * blockDim.x + threadIdx.x;
    if (r < NROWS) out_idx[r] = (float)(unsigned int)(best[r] & 0xFFFFFFFFull);
    if (r == 0) out_loss[0] = (float)(1.25 * (*accum) / 16777216.0);
}

extern "C" void kernel_launch(void* const* d_in, const int* in_sizes, int n_in,
                              void* d_out, int out_size, void* d_ws, size_t ws_size,
                              hipStream_t stream) {
    const float* X = (const float*)d_in[0];   // [32,1024,512] f32
    const float* E = (const float*)d_in[1];   // [8192,512]    f32

    float* out      = (float*)d_out;
    float* out_q    = out;                          // 16777216
    float* out_idx  = out + (size_t)NROWS * DIM;    // 32768
    float* out_loss = out_idx + NROWS;              // 1

    char* ws = (char*)d_ws;
    unsigned long long* best = (unsigned long long*)ws;
    float*  x2f   = (float*)(ws + 262144);
    double* accum = (double*)(ws + 393216);

    hipMemsetAsync(best, 0xFF, (size_t)NROWS * 8, stream);
    hipMemsetAsync(accum, 0, 8, stream);

    x2_kernel<<<NROWS / 4, 256, 0, stream>>>(X, x2f);

    if (ws_size >= WS_NEED) {
        unsigned short* Eb = (unsigned short*)(ws + 524288);
        unsigned short* Xb = (unsigned short*)(ws + 8912896);
        conv_kernel<<<(NEMB * 64) / 256, 256, 0, stream>>>(E, Eb, NEMB * 64);
        conv_kernel<<<(NROWS * 64) / 256, 256, 0, stream>>>(X, Xb, NROWS * 64);
        dim3 gridB(NROWS / BM, NEMB / BN);   // x = row panels (fast)
        dist_mfma7_kernel<<<gridB, 256, 0, stream>>>(X, E, Xb, Eb, x2f, best);
    } else {
        dim3 gridB(NROWS / BM, NEMB / BN);
        dist_mfma_kernel<<<gridB, 256, 0, stream>>>(X, E, x2f, best);
    }

    gather_loss_kernel<<<2048, 256, 0, stream>>>(X, E, best, out_q, accum);
    finalize_kernel<<<NROWS / 256, 256, 0, stream>>>(best, out_idx, out_loss, accum);
}

// Round 17
// 802.897 us; speedup vs baseline: 3.1069x; 1.0504x over previous
//
#include <hip/hip_runtime.h>
#include <stdint.h>

#define NROWS 32768   // 32*1024
#define DIM   512
#define NEMB  8192

#define BM 128
#define BN 128
#define BK 32
#define MARGIN 1.0e-4f   // validated r6/r7/r9

// ws layout (fast path):
//   [0,        262144) : ull best[NROWS]   key = (f2ord(exact_d)<<32) | idx
//   [262144,   393216) : float x2f[NROWS]
//   [393216,   393224) : double loss_accum
//   [524288,  8912896) : Eb  bf16 swizzled [8192][512]
//   [8912896,42467328) : Xb  bf16 swizzled [32768][512]
#define WS_NEED 42467328ull
//
// Reference model (validated rounds 4-16, PASSED 13x): ref d = fl32(x2-2*M),
// M = k-sequential f32 FMA chain; e2 vanishes under fl32(x2+e2); argmin
// first-occurrence = lowest index on bit-equal d. bf16-hi MFMA selects
// candidates (margin 1e-4); exact f32 chain re-scores -> bit-identical.
//
// r17: OCCUPANCY step 2. r16 confirmed the regime: launch_bounds(256,3)
// (VGPR 108->68, occ 19.5->28.9%) cut dist 945->802us -- the kernel scales
// with co-resident blocks, not schedule. Next quantum = 4 blocks/CU:
// regs <=128 (VGPR<=64 + 64 AGPR) via launch_bounds(256,4), LDS <=40KB via
// 2 buffers (33.3KB). Counted vmcnt(4) keeps the 1-deep prefetch in flight
// across barriers (not r7's drain). All else r9/r16-verbatim.

typedef short bf16x8 __attribute__((ext_vector_type(8)));   // 8 bf16 (4 VGPRs)
typedef float f32x4  __attribute__((ext_vector_type(4)));

#define LDSP(p) (__attribute__((address_space(3))) unsigned int*)(p)
#define GLP(p)  (const __attribute__((address_space(1))) unsigned int*)(p)

__device__ __forceinline__ unsigned int f2ord(float f) {
    unsigned int b = __float_as_uint(f);
    return b ^ ((b & 0x80000000u) ? 0xFFFFFFFFu : 0x80000000u);
}
__device__ __forceinline__ float ord2f(unsigned int o) {
    unsigned int b = (o & 0x80000000u) ? (o ^ 0x80000000u) : ~o;
    return __uint_as_float(b);
}
__device__ __forceinline__ unsigned short f2b(float f) {   // f32 -> bf16 RNE
    unsigned int u = __float_as_uint(f);
    u += 0x7FFFu + ((u >> 16) & 1u);
    return (unsigned short)(u >> 16);
}

// exact d for (row,col): the reference-matching sequential-k f32 FMA chain.
__device__ __forceinline__ float exact_d(const float* __restrict__ X,
                                         const float* __restrict__ E,
                                         float x2r, int row, int col) {
    const float* xp = X + (size_t)row * DIM;
    const float* ep = E + (size_t)col * DIM;
    float dot = 0.f;
    #pragma unroll 4
    for (int k = 0; k < DIM; k += 4) {
        float4 a  = *(const float4*)(xp + k);
        float4 bb = *(const float4*)(ep + k);
        dot = fmaf(a.x, bb.x, dot); dot = fmaf(a.y, bb.y, dot);
        dot = fmaf(a.z, bb.z, dot); dot = fmaf(a.w, bb.w, dot);
    }
    return x2r - 2.0f * dot;
}

// ||x_row||^2 in f64, rounded to f32 — unchanged (passed 13x)
__global__ __launch_bounds__(256)
void x2_kernel(const float* __restrict__ X, float* __restrict__ x2f) {
    int w = (int)((blockIdx.x * blockDim.x + threadIdx.x) >> 6);
    int lane = threadIdx.x & 63;
    if (w >= NROWS) return;
    const float4* row = (const float4*)(X + (size_t)w * DIM);
    double s = 0.0;
    #pragma unroll
    for (int i = 0; i < 2; ++i) {
        float4 v = row[lane + i * 64];
        s += (double)v.x * v.x + (double)v.y * v.y
           + (double)v.z * v.z + (double)v.w * v.w;
    }
    #pragma unroll
    for (int off = 32; off; off >>= 1) s += __shfl_down(s, off, 64);
    if (lane == 0) x2f[w] = (float)s;
}

// f32 -> bf16 RNE convert with chunk swizzle v2 — unchanged (passed r7-r16)
__global__ __launch_bounds__(256)
void conv_kernel(const float* __restrict__ src, unsigned short* __restrict__ dst,
                 int total) {
    int tid = blockIdx.x * 256 + threadIdx.x;
    if (tid >= total) return;
    int r   = tid >> 6;
    int cg  = tid & 63;
    int seg = cg >> 2, c = cg & 3;
    const float4* s = (const float4*)(src + (size_t)r * DIM + cg * 8);
    float4 v0 = s[0], v1 = s[1];
    unsigned int w0 = (unsigned)f2b(v0.x) | ((unsigned)f2b(v0.y) << 16);
    unsigned int w1 = (unsigned)f2b(v0.z) | ((unsigned)f2b(v0.w) << 16);
    unsigned int w2 = (unsigned)f2b(v1.x) | ((unsigned)f2b(v1.y) << 16);
    unsigned int w3 = (unsigned)f2b(v1.z) | ((unsigned)f2b(v1.w) << 16);
    int dchunk = seg * 4 + (c ^ ((r >> 1) & 3));
    *(uint4*)(dst + (size_t)r * DIM + dchunk * 8) = make_uint4(w0, w1, w2, w3);
}

// r9/r16 kernel with 2 LDS buffers + launch_bounds(256,4) -> 4 blocks/CU.
__global__ __launch_bounds__(256, 4)
void dist_mfma8_kernel(const float* __restrict__ X, const float* __restrict__ E,
                       const unsigned short* __restrict__ Xb,
                       const unsigned short* __restrict__ Eb,
                       const float* __restrict__ x2f,
                       unsigned long long* __restrict__ best) {
    __shared__ unsigned short As[2][BM][BK];   // 2 x 8 KB, LINEAR (DMA dest)
    __shared__ unsigned short Bs[2][BN][BK];   // 2 x 8 KB
    __shared__ unsigned int   smin[BM];

    const int t    = threadIdx.x;
    const int lane = t & 63;
    const int wid  = t >> 6;
    const int wm   = (wid >> 1) * 64;
    const int wn   = (wid & 1) * 64;
    const int rowBase = blockIdx.x * BM;   // x = row panels (fast) -> warm prune
    const int colBase = blockIdx.y * BN;

    if (t < BM) smin[t] = 0xFFFFFFFFu;

    const char* aSrc = (const char*)Xb
        + (size_t)(rowBase + wid * 16 + (lane >> 2)) * 1024 + (size_t)(lane & 3) * 16;
    const char* bSrc = (const char*)Eb
        + (size_t)(colBase + wid * 16 + (lane >> 2)) * 1024 + (size_t)(lane & 3) * 16;

    // fragment read: row = base + (lane&15); logical chunk koff=(lane>>4) at
    // physical slot koff ^ ((row>>1)&3) = koff ^ ((lane>>1)&3)  [r7-validated]
    const int fswz = (((lane >> 4) ^ ((lane >> 1) & 3)) << 4);
    const int aOff = (wm + (lane & 15)) * 64 + fswz;
    const int bOff = (wn + (lane & 15)) * 64 + fswz;

    f32x4 acc[4][4] = {};

#define ISSUE_TILE(KT, BUF) do {                                               \
        const char* an_ = aSrc + (KT) * 64;                                    \
        const char* bn_ = bSrc + (KT) * 64;                                    \
        __builtin_amdgcn_global_load_lds(GLP(an_),         LDSP(&As[BUF][wid * 16][0]),      16, 0, 0); \
        __builtin_amdgcn_global_load_lds(GLP(an_ + 65536), LDSP(&As[BUF][64 + wid * 16][0]), 16, 0, 0); \
        __builtin_amdgcn_global_load_lds(GLP(bn_),         LDSP(&Bs[BUF][wid * 16][0]),      16, 0, 0); \
        __builtin_amdgcn_global_load_lds(GLP(bn_ + 65536), LDSP(&Bs[BUF][64 + wid * 16][0]), 16, 0, 0); \
    } while (0)

#define COMPUTE_TILE(BUF) do {                                                 \
        const char* aR_ = (const char*)&As[BUF][0][0] + aOff;                  \
        const char* bR_ = (const char*)&Bs[BUF][0][0] + bOff;                  \
        bf16x8 af_[4], bg_[4];                                                 \
        _Pragma("unroll")                                                      \
        for (int mi = 0; mi < 4; ++mi)                                         \
            af_[mi] = *(const bf16x8*)(aR_ + mi * 16 * 64);                    \
        _Pragma("unroll")                                                      \
        for (int nj = 0; nj < 4; ++nj)                                         \
            bg_[nj] = *(const bf16x8*)(bR_ + nj * 16 * 64);                    \
        _Pragma("unroll")                                                      \
        for (int mi = 0; mi < 4; ++mi)                                         \
            _Pragma("unroll")                                                  \
            for (int nj = 0; nj < 4; ++nj)                                     \
                acc[mi][nj] = __builtin_amdgcn_mfma_f32_16x16x32_bf16(         \
                    af_[mi], bg_[nj], acc[mi][nj], 0, 0, 0);                   \
    } while (0)

// Step KT: issue tile KT+1 into buf (KT+1)&1 (read last at step KT-1, whose
// trailing lgkmcnt(0)+barrier precedes these issues); counted vmcnt(4)
// retires exactly tile KT (outstanding: KT (4) + KT+1 (4) = 8 -> wait 4).
#define K_STEP(KT, WAITSTR) do {                                               \
        if ((KT) + 1 < 16) ISSUE_TILE((KT) + 1, ((KT) + 1) & 1);               \
        asm volatile("s_waitcnt vmcnt(" WAITSTR ")" ::: "memory");             \
        __builtin_amdgcn_s_barrier();                                          \
        COMPUTE_TILE((KT) & 1);                                                \
        asm volatile("s_waitcnt lgkmcnt(0)" ::: "memory");                     \
        __builtin_amdgcn_s_barrier();                                          \
    } while (0)

    ISSUE_TILE(0, 0);

    K_STEP(0,  "4");  K_STEP(1,  "4");  K_STEP(2,  "4");  K_STEP(3,  "4");
    K_STEP(4,  "4");  K_STEP(5,  "4");  K_STEP(6,  "4");  K_STEP(7,  "4");
    K_STEP(8,  "4");  K_STEP(9,  "4");  K_STEP(10, "4");  K_STEP(11, "4");
    K_STEP(12, "4");  K_STEP(13, "4");  K_STEP(14, "4");  K_STEP(15, "0");

#undef K_STEP
#undef COMPUTE_TILE
#undef ISSUE_TILE

    // ---- block-local per-row min of s~ = -2*acc (r9 verbatim) ----
    #pragma unroll
    for (int mi = 0; mi < 4; ++mi)
        #pragma unroll
        for (int r = 0; r < 4; ++r) {
            float m4 = fminf(fminf(-2.f * acc[mi][0][r], -2.f * acc[mi][1][r]),
                             fminf(-2.f * acc[mi][2][r], -2.f * acc[mi][3][r]));
            unsigned u = f2ord(m4);
            #pragma unroll
            for (int sh = 1; sh < 16; sh <<= 1)
                u = min(u, (unsigned)__shfl_xor((int)u, sh, 64));
            if ((lane & 15) == 0)
                atomicMin(&smin[wm + mi * 16 + (lane >> 4) * 4 + r], u);
        }
    __syncthreads();

    // ---- candidate mask: s~ <= min(block_min, global_best - x2) + MARGIN ----
    unsigned long long mask = 0;
    #pragma unroll
    for (int mi = 0; mi < 4; ++mi)
        #pragma unroll
        for (int r = 0; r < 4; ++r) {
            int rt  = wm + mi * 16 + (lane >> 4) * 4 + r;
            int row = rowBase + rt;
            float x2v = x2f[row];
            float dg  = ord2f((unsigned)(best[row] >> 32));   // NaN if sentinel
            float th  = fminf(ord2f(smin[rt]), dg - x2v) + MARGIN;  // NaN-safe
            #pragma unroll
            for (int nj = 0; nj < 4; ++nj) {
                float s = -2.f * acc[mi][nj][r];
                if (s <= th) mask |= 1ull << (mi * 16 + nj * 4 + r);
            }
        }

    // ---- exact refine (bit-identical chain, passed 13x) ----
    while (mask) {
        int b = __builtin_ctzll(mask);
        mask &= mask - 1;
        int mi = b >> 4, nj = (b >> 2) & 3, r = b & 3;
        int row = rowBase + wm + mi * 16 + (lane >> 4) * 4 + r;
        int col = colBase + wn + nj * 16 + (lane & 15);
        float d = exact_d(X, E, x2f[row], row, col);
        unsigned long long key = ((unsigned long long)f2ord(d) << 32) | (unsigned)col;
        atomicMin(&best[row], key);
    }
}

// ---------- round-5 kernel kept as last-resort fallback (tiny ws) ----------
__global__ __launch_bounds__(256)
void dist_mfma_kernel(const float* __restrict__ X, const float* __restrict__ E,
                      const float* __restrict__ x2f,
                      unsigned long long* __restrict__ best) {
    __shared__ unsigned short Asf[BM][40];
    __shared__ unsigned short Bsf[BN][40];
    __shared__ unsigned int   smin[BM];

    const int t    = threadIdx.x;
    const int lane = t & 63;
    const int wid  = t >> 6;
    const int wm   = (wid >> 1) * 64;
    const int wn   = (wid & 1) * 64;
    const int rowBase = blockIdx.x * BM;
    const int colBase = blockIdx.y * BN;

    if (t < BM) smin[t] = 0xFFFFFFFFu;

    const int srow = t >> 3;
    const int sf4  = t & 7;

    f32x4 acc[4][4] = {};
    float4 ra[4], rb[4];

    #pragma unroll
    for (int p = 0; p < 4; ++p) {
        ra[p] = *(const float4*)(X + (size_t)(rowBase + p * 32 + srow) * DIM + sf4 * 4);
        rb[p] = *(const float4*)(E + (size_t)(colBase + p * 32 + srow) * DIM + sf4 * 4);
    }

    for (int kt = 0; kt < DIM / BK; ++kt) {
        __syncthreads();
        #pragma unroll
        for (int p = 0; p < 4; ++p) {
            int r = p * 32 + srow;
            unsigned int alo = (unsigned)f2b(ra[p].x) | ((unsigned)f2b(ra[p].y) << 16);
            unsigned int ahi = (unsigned)f2b(ra[p].z) | ((unsigned)f2b(ra[p].w) << 16);
            *(uint2*)&Asf[r][sf4 * 4] = make_uint2(alo, ahi);
            unsigned int blo = (unsigned)f2b(rb[p].x) | ((unsigned)f2b(rb[p].y) << 16);
            unsigned int bhi = (unsigned)f2b(rb[p].z) | ((unsigned)f2b(rb[p].w) << 16);
            *(uint2*)&Bsf[r][sf4 * 4] = make_uint2(blo, bhi);
        }
        __syncthreads();

        if (kt + 1 < DIM / BK) {
            int k0 = (kt + 1) * BK;
            #pragma unroll
            for (int p = 0; p < 4; ++p) {
                ra[p] = *(const float4*)(X + (size_t)(rowBase + p * 32 + srow) * DIM + k0 + sf4 * 4);
                rb[p] = *(const float4*)(E + (size_t)(colBase + p * 32 + srow) * DIM + k0 + sf4 * 4);
            }
        }

        bf16x8 af[4], bg[4];
        #pragma unroll
        for (int mi = 0; mi < 4; ++mi)
            af[mi] = *(const bf16x8*)&Asf[wm + mi * 16 + (lane & 15)][(lane >> 4) * 8];
        #pragma unroll
        for (int nj = 0; nj < 4; ++nj)
            bg[nj] = *(const bf16x8*)&Bsf[wn + nj * 16 + (lane & 15)][(lane >> 4) * 8];
        #pragma unroll
        for (int mi = 0; mi < 4; ++mi)
            #pragma unroll
            for (int nj = 0; nj < 4; ++nj)
                acc[mi][nj] = __builtin_amdgcn_mfma_f32_16x16x32_bf16(
                    af[mi], bg[nj], acc[mi][nj], 0, 0, 0);
    }

    #pragma unroll
    for (int mi = 0; mi < 4; ++mi)
        #pragma unroll
        for (int r = 0; r < 4; ++r) {
            float m4 = fminf(fminf(-2.f * acc[mi][0][r], -2.f * acc[mi][1][r]),
                             fminf(-2.f * acc[mi][2][r], -2.f * acc[mi][3][r]));
            unsigned u = f2ord(m4);
            #pragma unroll
            for (int sh = 1; sh < 16; sh <<= 1)
                u = min(u, (unsigned)__shfl_xor((int)u, sh, 64));
            if ((lane & 15) == 0)
                atomicMin(&smin[wm + mi * 16 + (lane >> 4) * 4 + r], u);
        }
    __syncthreads();

    unsigned long long mask = 0;
    #pragma unroll
    for (int mi = 0; mi < 4; ++mi)
        #pragma unroll
        for (int r = 0; r < 4; ++r) {
            int rt  = wm + mi * 16 + (lane >> 4) * 4 + r;
            int row = rowBase + rt;
            float x2v = x2f[row];
            float dg  = ord2f((unsigned)(best[row] >> 32));
            float th  = fminf(ord2f(smin[rt]), dg - x2v) + 1.5e-3f;
            #pragma unroll
            for (int nj = 0; nj < 4; ++nj) {
                float s = -2.f * acc[mi][nj][r];
                if (s <= th) mask |= 1ull << (mi * 16 + nj * 4 + r);
            }
        }

    while (mask) {
        int b = __builtin_ctzll(mask);
        mask &= mask - 1;
        int mi = b >> 4, nj = (b >> 2) & 3, r = b & 3;
        int row = rowBase + wm + mi * 16 + (lane >> 4) * 4 + r;
        int col = colBase + wn + nj * 16 + (lane & 15);
        float d = exact_d(X, E, x2f[row], row, col);
        unsigned long long key = ((unsigned long long)f2ord(d) << 32) | (unsigned)col;
        atomicMin(&best[row], key);
    }
}

// gather quantized + accumulate squared-error loss — unchanged (passed 13x)
__global__ __launch_bounds__(256)
void gather_loss_kernel(const float* __restrict__ X, const float* __restrict__ E,
                        const unsigned long long* __restrict__ best,
                        float* __restrict__ out_q, double* __restrict__ accum) {
    __shared__ float wsum[4];
    const int t = threadIdx.x;
    const size_t base = (size_t)blockIdx.x * 8192;
    float local = 0.f;
    #pragma unroll 4
    for (int it = 0; it < 32; ++it) {
        size_t i = base + (size_t)it * 256 + t;
        int row = (int)(i >> 9);
        int d   = (int)(i & 511);
        unsigned int idx = (unsigned int)(best[row] & 0xFFFFFFFFull);
        float q = E[(size_t)idx * DIM + d];
        float x = X[i];
        out_q[i] = q;
        float df = q - x;
        local = fmaf(df, df, local);
    }
    #pragma unroll
    for (int off = 32; off; off >>= 1) local += __shfl_down(local, off, 64);
    int lane = t & 63, w = t >> 6;
    if (lane == 0) wsum[w] = local;
    __syncthreads();
    if (t == 0) {
        float s = wsum[0] + wsum[1] + wsum[2] + wsum[3];
        atomicAdd(accum, (double)s);
    }
}

__global__ __launch_bounds__(256)
void finalize_kernel(const unsigned long long* __restrict__ best,
                     float* __restrict__ out_idx, float* __restrict__ out_loss,
                     const double* __restrict__ accum) {
    int r = blockIdx.x * blockDim.x + threadIdx.x;
    if (r < NROWS) out_idx[r] = (float)(unsigned int)(best[r] & 0xFFFFFFFFull);
    if (r == 0) out_loss[0] = (float)(1.25 * (*accum) / 16777216.0);
}

extern "C" void kernel_launch(void* const* d_in, const int* in_sizes, int n_in,
                              void* d_out, int out_size, void* d_ws, size_t ws_size,
                              hipStream_t stream) {
    const float* X = (const float*)d_in[0];   // [32,1024,512] f32
    const float* E = (const float*)d_in[1];   // [8192,512]    f32

    float* out      = (float*)d_out;
    float* out_q    = out;                          // 16777216
    float* out_idx  = out + (size_t)NROWS * DIM;    // 32768
    float* out_loss = out_idx + NROWS;              // 1

    char* ws = (char*)d_ws;
    unsigned long long* best = (unsigned long long*)ws;
    float*  x2f   = (float*)(ws + 262144);
    double* accum = (double*)(ws + 393216);

    hipMemsetAsync(best, 0xFF, (size_t)NROWS * 8, stream);
    hipMemsetAsync(accum, 0, 8, stream);

    x2_kernel<<<NROWS / 4, 256, 0, stream>>>(X, x2f);

    if (ws_size >= WS_NEED) {
        unsigned short* Eb = (unsigned short*)(ws + 524288);
        unsigned short* Xb = (unsigned short*)(ws + 8912896);
        conv_kernel<<<(NEMB * 64) / 256, 256, 0, stream>>>(E, Eb, NEMB * 64);
        conv_kernel<<<(NROWS * 64) / 256, 256, 0, stream>>>(X, Xb, NROWS * 64);
        dim3 gridB(NROWS / BM, NEMB / BN);   // x = row panels (fast)
        dist_mfma8_kernel<<<gridB, 256, 0, stream>>>(X, E, Xb, Eb, x2f, best);
    } else {
        dim3 gridB(NROWS / BM, NEMB / BN);
        dist_mfma_kernel<<<gridB, 256, 0, stream>>>(X, E, x2f, best);
    }

    gather_loss_kernel<<<2048, 256, 0, stream>>>(X, E, best, out_q, accum);
    finalize_kernel<<<NROWS / 256, 256, 0, stream>>>(best, out_idx, out_loss, accum);
}